// Round 2
// baseline (135.468 us; speedup 1.0000x reference)
//
#include <hip/hip_runtime.h>
#include <hip/hip_bf16.h>
#include <stdint.h>

#define E_ 8
#define H_ 1024
#define I_ 1024
#define T_ 8192
#define BM 128
#define BK 32
#define NKT1 (H_ / BK)
#define NKT2 (I_ / BK)

typedef __attribute__((ext_vector_type(4))) float f32x4;
typedef __attribute__((ext_vector_type(8))) short bf16x8;

__device__ __forceinline__ unsigned short f2bf(float f) {
  union { float f; unsigned int u; } v; v.f = f;
  unsigned int lsb = (v.u >> 16) & 1u;
  v.u += 0x7fffu + lsb;          // round-to-nearest-even
  return (unsigned short)(v.u >> 16);
}

__device__ __forceinline__ void gload_lds16(const void* g, void* l) {
  __builtin_amdgcn_global_load_lds(
      (const __attribute__((address_space(1))) unsigned int*)g,
      (__attribute__((address_space(3))) unsigned int*)l,
      16, 0, 0);
}

// ---------------- conversion: f32 -> bf16, vectorized ----------------
__global__ void convert_f32_bf16(const float* __restrict__ in,
                                 unsigned short* __restrict__ out, int n) {
  int i = (blockIdx.x * blockDim.x + threadIdx.x) * 4;
  if (i >= n) return;
  float4 v = *reinterpret_cast<const float4*>(in + i);
  ushort4 o;
  o.x = f2bf(v.x); o.y = f2bf(v.y); o.z = f2bf(v.z); o.w = f2bf(v.w);
  *reinterpret_cast<ushort4*>(out + i) = o;
}

// ------------- transpose+convert: [E][R][C] f32 -> [E][C][R] bf16 -------------
__global__ void transpose_f32_to_bf16(const float* __restrict__ in,
                                      unsigned short* __restrict__ out,
                                      int R, int C) {
  __shared__ float tile[32][33];
  int e = blockIdx.z;
  const float* inp = in + (size_t)e * R * C;
  unsigned short* outp = out + (size_t)e * R * C;
  int c0 = blockIdx.x * 32, r0 = blockIdx.y * 32;
  for (int rr = threadIdx.y; rr < 32; rr += 8)
    tile[rr][threadIdx.x] = inp[(size_t)(r0 + rr) * C + c0 + threadIdx.x];
  __syncthreads();
  for (int rr = threadIdx.y; rr < 32; rr += 8)
    outp[(size_t)(c0 + rr) * R + r0 + threadIdx.x] = f2bf(tile[threadIdx.x][rr]);
}

// ------------- expert lookup from device-side counts -------------
__device__ __forceinline__ bool find_tile(const int* counts, int ty,
                                          int& row_start, int& rows) {
  int tacc = 0, off = 0;
  int expert = -1;
  #pragma unroll
  for (int e = 0; e < E_; ++e) {
    int c = counts[e];
    int te = (c + BM - 1) >> 7;
    if (expert < 0 && ty < tacc + te) {
      expert = e;
      int lt = ty - tacc;
      row_start = off + lt * BM;
      rows = min(BM, c - lt * BM);
    }
    tacc += te; off += c;
  }
  if (expert < 0) return false;
  row_start |= (expert << 24);
  return true;
}

// ---------------- GEMM1 + SwiGLU (2-phase dbuf) ----------------
// X [T][H] bf16, W1T [E][2I][H] bf16 -> H [T][I] bf16
// 1-D grid nwg = 16 * 72 (XCD-bijective remap), 256 thr (4 waves x 32 rows x 128 n)
__launch_bounds__(256, 3)
__global__ void gemm1_swiglu(const unsigned short* __restrict__ X,
                             const unsigned short* __restrict__ W1T,
                             const int* __restrict__ counts,
                             unsigned short* __restrict__ Hout) {
  __shared__ unsigned short As[2][BM * BK];
  __shared__ unsigned short Bs[2][BM * BK];
  int nwg = gridDim.x;
  int id = blockIdx.x;
  int swz = (id & 7) * (nwg >> 3) + (id >> 3);   // bijective: nwg % 8 == 0
  int bn = swz & 15;
  int ty = swz >> 4;
  int row_start = 0, rows = 0;
  if (!find_tile(counts, ty, row_start, rows)) return;
  int expert = row_start >> 24; row_start &= 0xFFFFFF;
  int tid = threadIdx.x, wid = tid >> 6, lane = tid & 63;
  const unsigned short* Wp = W1T + (size_t)expert * (2 * I_) * H_;

  f32x4 acc[2][8];
  #pragma unroll
  for (int m = 0; m < 2; ++m)
    #pragma unroll
    for (int n = 0; n < 8; ++n) acc[m][n] = {0.f, 0.f, 0.f, 0.f};

  int l4 = lane >> 2;                               // staging row within 16-row group
  int csw = ((lane & 3) ^ ((l4 >> 1) & 3)) * 8;     // pre-swizzled global k-chunk
  int lr = lane & 15;
  int ck = ((lane >> 4) ^ ((lr >> 1) & 3)) * 8;     // swizzled ds_read k-chunk

#define STAGE1(buf, kt) do {                                                   \
    int k0 = (kt) * BK;                                                        \
    _Pragma("unroll")                                                          \
    for (int i = 0; i < 2; ++i) {                                              \
      int rl = wid * 32 + i * 16 + l4;                                         \
      int gr = row_start + min(rl, rows - 1);                                  \
      gload_lds16(X + (size_t)gr * H_ + k0 + csw,                              \
                  &As[buf][(wid * 32 + i * 16) * BK]);                         \
    }                                                                          \
    _Pragma("unroll")                                                          \
    for (int i = 0; i < 2; ++i) {                                              \
      int ln = wid * 32 + i * 16 + l4;                                         \
      int gn = bn * 64 + ln + ((ln >= 64) ? (I_ - 64) : 0);                    \
      gload_lds16(Wp + (size_t)gn * H_ + k0 + csw,                             \
                  &Bs[buf][(wid * 32 + i * 16) * BK]);                         \
    }                                                                          \
  } while (0)

  STAGE1(0, 0);
  __syncthreads();
  for (int kt = 0; kt < NKT1; ++kt) {
    int cur = kt & 1;
    if (kt + 1 < NKT1) STAGE1(cur ^ 1, kt + 1);
    bf16x8 a[2], b[8];
    #pragma unroll
    for (int m = 0; m < 2; ++m)
      a[m] = *reinterpret_cast<const bf16x8*>(&As[cur][(wid * 32 + m * 16 + lr) * BK + ck]);
    #pragma unroll
    for (int n = 0; n < 8; ++n)
      b[n] = *reinterpret_cast<const bf16x8*>(&Bs[cur][(n * 16 + lr) * BK + ck]);
    #pragma unroll
    for (int m = 0; m < 2; ++m)
      #pragma unroll
      for (int n = 0; n < 8; ++n)
        acc[m][n] = __builtin_amdgcn_mfma_f32_16x16x32_bf16(a[m], b[n], acc[m][n], 0, 0, 0);
    __syncthreads();
  }
#undef STAGE1

  int lq = lane >> 4;
  #pragma unroll
  for (int m = 0; m < 2; ++m)
    #pragma unroll
    for (int n = 0; n < 4; ++n) {
      f32x4 g = acc[m][n], u = acc[m][n + 4];
      #pragma unroll
      for (int r = 0; r < 4; ++r) {
        int rl = wid * 32 + m * 16 + lq * 4 + r;
        if (rl < rows) {
          float gv = g[r];
          float hv = (gv / (1.f + __expf(-gv))) * u[r];
          Hout[(size_t)(row_start + rl) * I_ + bn * 64 + n * 16 + lr] = f2bf(hv);
        }
      }
    }
}

// ---------------- GEMM2 (2-phase dbuf) ----------------
// Hin [T][I] bf16, W2T [E][H][I] bf16 -> Out [T][H] f32
// 1-D grid nwg = 8 * 72, 256 thr (4 waves 2x2, each 64x64)
__launch_bounds__(256, 3)
__global__ void gemm2(const unsigned short* __restrict__ Hin,
                      const unsigned short* __restrict__ W2T,
                      const int* __restrict__ counts,
                      float* __restrict__ Out) {
  __shared__ unsigned short As[2][BM * BK];
  __shared__ unsigned short Bs[2][BM * BK];
  int nwg = gridDim.x;
  int id = blockIdx.x;
  int swz = (id & 7) * (nwg >> 3) + (id >> 3);
  int bn = swz & 7;
  int ty = swz >> 3;
  int row_start = 0, rows = 0;
  if (!find_tile(counts, ty, row_start, rows)) return;
  int expert = row_start >> 24; row_start &= 0xFFFFFF;
  int tid = threadIdx.x, wid = tid >> 6, lane = tid & 63;
  int wr = wid >> 1, wc = wid & 1;
  const unsigned short* Wp = W2T + (size_t)expert * H_ * I_;

  f32x4 acc[4][4];
  #pragma unroll
  for (int m = 0; m < 4; ++m)
    #pragma unroll
    for (int n = 0; n < 4; ++n) acc[m][n] = {0.f, 0.f, 0.f, 0.f};

  int l4 = lane >> 2;
  int csw = ((lane & 3) ^ ((l4 >> 1) & 3)) * 8;
  int lr = lane & 15;
  int ck = ((lane >> 4) ^ ((lr >> 1) & 3)) * 8;

#define STAGE2(buf, kt) do {                                                   \
    int k0 = (kt) * BK;                                                        \
    _Pragma("unroll")                                                          \
    for (int i = 0; i < 2; ++i) {                                              \
      int rl = wid * 32 + i * 16 + l4;                                         \
      int gr = row_start + min(rl, rows - 1);                                  \
      gload_lds16(Hin + (size_t)gr * I_ + k0 + csw,                            \
                  &As[buf][(wid * 32 + i * 16) * BK]);                         \
    }                                                                          \
    _Pragma("unroll")                                                          \
    for (int i = 0; i < 2; ++i) {                                              \
      int ln = wid * 32 + i * 16 + l4;                                         \
      int gn = bn * 128 + ln;                                                  \
      gload_lds16(Wp + (size_t)gn * I_ + k0 + csw,                             \
                  &Bs[buf][(wid * 32 + i * 16) * BK]);                         \
    }                                                                          \
  } while (0)

  STAGE2(0, 0);
  __syncthreads();
  for (int kt = 0; kt < NKT2; ++kt) {
    int cur = kt & 1;
    if (kt + 1 < NKT2) STAGE2(cur ^ 1, kt + 1);
    bf16x8 a[4], b[4];
    #pragma unroll
    for (int m = 0; m < 4; ++m)
      a[m] = *reinterpret_cast<const bf16x8*>(&As[cur][(wr * 64 + m * 16 + lr) * BK + ck]);
    #pragma unroll
    for (int n = 0; n < 4; ++n)
      b[n] = *reinterpret_cast<const bf16x8*>(&Bs[cur][(wc * 64 + n * 16 + lr) * BK + ck]);
    #pragma unroll
    for (int m = 0; m < 4; ++m)
      #pragma unroll
      for (int n = 0; n < 4; ++n)
        acc[m][n] = __builtin_amdgcn_mfma_f32_16x16x32_bf16(a[m], b[n], acc[m][n], 0, 0, 0);
    __syncthreads();
  }
#undef STAGE2

  int lq = lane >> 4;
  #pragma unroll
  for (int m = 0; m < 4; ++m)
    #pragma unroll
    for (int n = 0; n < 4; ++n)
      #pragma unroll
      for (int r = 0; r < 4; ++r) {
        int rl = wr * 64 + m * 16 + lq * 4 + r;
        if (rl < rows)
          Out[(size_t)(row_start + rl) * H_ + bn * 128 + wc * 64 + n * 16 + lr] =
              acc[m][n][r];
      }
}

extern "C" void kernel_launch(void* const* d_in, const int* in_sizes, int n_in,
                              void* d_out, int out_size, void* d_ws, size_t ws_size,
                              hipStream_t stream) {
  const float* x  = (const float*)d_in[0];
  const float* w1 = (const float*)d_in[1];   // [E][H][2I]
  const float* w2 = (const float*)d_in[2];   // [E][I][H]
  const int* counts = (const int*)d_in[3];
  float* out = (float*)d_out;

  char* ws = (char*)d_ws;
  unsigned short* xb  = (unsigned short*)ws;
  unsigned short* w1t = (unsigned short*)(ws + (size_t)T_ * H_ * 2);
  unsigned short* w2t = (unsigned short*)(ws + (size_t)T_ * H_ * 2
                                             + (size_t)E_ * 2 * I_ * H_ * 2);
  unsigned short* hbuf = (unsigned short*)(ws + (size_t)T_ * H_ * 2
                                              + (size_t)E_ * 2 * I_ * H_ * 2
                                              + (size_t)E_ * H_ * I_ * 2);

  // 1) convert x
  convert_f32_bf16<<<(T_ * H_) / 1024, 256, 0, stream>>>(x, xb, T_ * H_);
  // 2) transpose+convert weights
  dim3 tb(32, 8);
  transpose_f32_to_bf16<<<dim3((2 * I_) / 32, H_ / 32, E_), tb, 0, stream>>>(w1, w1t, H_, 2 * I_);
  transpose_f32_to_bf16<<<dim3(H_ / 32, I_ / 32, E_), tb, 0, stream>>>(w2, w2t, I_, H_);
  // 3) grouped GEMM1 + SwiGLU  (1-D grid, XCD-swizzled; 16*72 % 8 == 0)
  int max_tiles = T_ / BM + E_;                    // 72
  gemm1_swiglu<<<16 * max_tiles, 256, 0, stream>>>(xb, w1t, counts, hbuf);
  // 4) grouped GEMM2  (8*72 % 8 == 0)
  gemm2<<<8 * max_tiles, 256, 0, stream>>>(hbuf, w2t, counts, out);
}

// Round 3
// 120.402 us; speedup vs baseline: 1.1251x; 1.1251x over previous
//
#include <hip/hip_runtime.h>
#include <hip/hip_bf16.h>
#include <stdint.h>

#define E_ 8
#define H_ 1024
#define I_ 1024
#define T_ 8192
#define BM 128
#define BK 32
#define NKT 32               // K/BK for both GEMMs (H_=I_=1024)

typedef __attribute__((ext_vector_type(4))) float f32x4;
typedef __attribute__((ext_vector_type(8))) short bf16x8;

__device__ __forceinline__ unsigned short f2bf(float f) {
  union { float f; unsigned int u; } v; v.f = f;
  unsigned int lsb = (v.u >> 16) & 1u;
  v.u += 0x7fffu + lsb;
  return (unsigned short)(v.u >> 16);
}

__device__ __forceinline__ void gload_lds16(const void* g, void* l) {
  __builtin_amdgcn_global_load_lds(
      (const __attribute__((address_space(1))) unsigned int*)g,
      (__attribute__((address_space(3))) unsigned int*)l,
      16, 0, 0);
}

// ---------------- conversion: f32 -> bf16 ----------------
__global__ void convert_f32_bf16(const float* __restrict__ in,
                                 unsigned short* __restrict__ out, int n) {
  int i = (blockIdx.x * blockDim.x + threadIdx.x) * 4;
  if (i >= n) return;
  float4 v = *reinterpret_cast<const float4*>(in + i);
  ushort4 o;
  o.x = f2bf(v.x); o.y = f2bf(v.y); o.z = f2bf(v.z); o.w = f2bf(v.w);
  *reinterpret_cast<ushort4*>(out + i) = o;
}

// ------------- transpose+convert: [E][R][C] f32 -> [E][C][R] bf16 -------------
// 64x32 in-tiles, ushort2 stores (256B/wave store segments)
__global__ void transpose_f32_to_bf16(const float* __restrict__ in,
                                      unsigned short* __restrict__ out,
                                      int R, int C) {
  __shared__ float tile[64][33];
  int e = blockIdx.z;
  const float* inp = in + (size_t)e * R * C;
  unsigned short* outp = out + (size_t)e * R * C;
  int c0 = blockIdx.x * 32, r0 = blockIdx.y * 64;
  int tx = threadIdx.x, ty = threadIdx.y;      // 32 x 8
  for (int rr = ty; rr < 64; rr += 8)
    tile[rr][tx] = inp[(size_t)(r0 + rr) * C + c0 + tx];
  __syncthreads();
  // out row c (32 rows), 64 elems each; thread handles pairs (2*tx, 2*tx+1)
  for (int cc = ty; cc < 32; cc += 8) {
    ushort2 o;
    o.x = f2bf(tile[2 * tx][cc]);
    o.y = f2bf(tile[2 * tx + 1][cc]);
    *reinterpret_cast<ushort2*>(&outp[(size_t)(c0 + cc) * R + r0 + 2 * tx]) = o;
  }
}

// ------------- expert lookup -------------
__device__ __forceinline__ void find_tile(const int* counts, int ty,
                                          int& row_start, int& rows, int& expert) {
  int tacc = 0, off = 0;
  expert = 0; row_start = 0; rows = BM;
  #pragma unroll
  for (int e = 0; e < E_; ++e) {
    int c = counts[e];
    int te = (c + BM - 1) >> 7;
    if (ty >= tacc && ty < tacc + te) {
      expert = e;
      int lt = ty - tacc;
      row_start = off + lt * BM;
      rows = min(BM, c - lt * BM);
    }
    tacc += te; off += c;
  }
}

// =====================================================================
// GEMM1 + SwiGLU: X [T][H] bf16 x W1T [E][2I][H] bf16 -> Hout [T][I] bf16
// block tile 128 rows x 256 B-rows (128 gate + 128 up cols interleaved by wave)
// 4 waves 2x2, wave tile 64 x 128; BK=32; counted-vmcnt dbuf.
// grid 512 = 8 bn x 64 ty, XCD-swizzled.
// =====================================================================
__launch_bounds__(256, 2)
__global__ void gemm1_swiglu(const unsigned short* __restrict__ X,
                             const unsigned short* __restrict__ W1T,
                             const int* __restrict__ counts,
                             unsigned short* __restrict__ Hout) {
  __shared__ unsigned short As[2][BM * BK];        // 128 x 32
  __shared__ unsigned short Bs[2][256 * BK];       // 256 x 32
  int id = blockIdx.x;
  int swz = (id & 7) * 64 + (id >> 3);             // 512 % 8 == 0, bijective
  int bn = swz & 7;                                // output col block (128 wide)
  int tyid = swz >> 3;                             // M tile 0..63
  int row_start, rows, expert;
  find_tile(counts, tyid, row_start, rows, expert);
  int tid = threadIdx.x, wid = tid >> 6, lane = tid & 63;
  int wr = wid >> 1, wc = wid & 1;
  const unsigned short* Wp = W1T + (size_t)expert * (2 * I_) * H_;

  f32x4 acc[4][8];
  #pragma unroll
  for (int m = 0; m < 4; ++m)
    #pragma unroll
    for (int n = 0; n < 8; ++n) acc[m][n] = {0.f, 0.f, 0.f, 0.f};

  int l4 = lane >> 2;                              // row within 16-row group
  int csw = ((lane & 3) ^ ((l4 >> 1) & 3)) * 8;    // pre-swizzled k-chunk (global src)
  int lr = lane & 15;
  int ck = ((lane >> 4) ^ ((lr >> 1) & 3)) * 8;    // swizzled ds_read k-chunk

  // B LDS row r -> w1t global row: [wc*128 + 0..63]=gate cols, [+64..127]=up cols
#define B1ROW(r) (((((r) >> 6) & 1) ? I_ : 0) + bn * 128 + (((r) >> 7) * 64) + ((r) & 63))

  // per-wave: 2 A groups (rows 32w..), 4 B groups (rows 64w..) => 6 gload_lds
#define STAGE1(buf, kt) do {                                                   \
    int k0 = (kt) * BK + csw;                                                  \
    _Pragma("unroll")                                                          \
    for (int i = 0; i < 2; ++i) {                                              \
      int r = wid * 32 + i * 16;                                               \
      int gr = row_start + min(r + l4, rows - 1);                              \
      gload_lds16(X + (size_t)gr * H_ + k0, &As[buf][r * BK]);                 \
    }                                                                          \
    _Pragma("unroll")                                                          \
    for (int i = 0; i < 4; ++i) {                                              \
      int r = wid * 64 + i * 16;                                               \
      int gn = B1ROW(r + l4);                                                  \
      gload_lds16(Wp + (size_t)gn * H_ + k0, &Bs[buf][r * BK]);                \
    }                                                                          \
  } while (0)

  STAGE1(0, 0);
  int cur = 0;
  for (int kt = 0; kt < NKT; ++kt) {
    STAGE1(cur ^ 1, min(kt + 1, NKT - 1));
    asm volatile("s_waitcnt vmcnt(6)" ::: "memory");
    __builtin_amdgcn_sched_barrier(0);
    __builtin_amdgcn_s_barrier();
    bf16x8 a[4], b[8];
    #pragma unroll
    for (int m = 0; m < 4; ++m)
      a[m] = *reinterpret_cast<const bf16x8*>(&As[cur][(wr * 64 + m * 16 + lr) * BK + ck]);
    #pragma unroll
    for (int n = 0; n < 8; ++n)
      b[n] = *reinterpret_cast<const bf16x8*>(&Bs[cur][(wc * 128 + n * 16 + lr) * BK + ck]);
    __builtin_amdgcn_s_setprio(1);
    #pragma unroll
    for (int m = 0; m < 4; ++m)
      #pragma unroll
      for (int n = 0; n < 8; ++n)
        acc[m][n] = __builtin_amdgcn_mfma_f32_16x16x32_bf16(a[m], b[n], acc[m][n], 0, 0, 0);
    __builtin_amdgcn_s_setprio(0);
    __builtin_amdgcn_sched_barrier(0);
    __builtin_amdgcn_s_barrier();
    cur ^= 1;
  }
#undef STAGE1
#undef B1ROW

  int lq = lane >> 4;
  #pragma unroll
  for (int m = 0; m < 4; ++m)
    #pragma unroll
    for (int n = 0; n < 4; ++n) {
      f32x4 g = acc[m][n], u = acc[m][n + 4];
      #pragma unroll
      for (int r = 0; r < 4; ++r) {
        int rl = wr * 64 + m * 16 + lq * 4 + r;
        if (rl < rows) {
          float gv = g[r];
          float hv = (gv / (1.f + __expf(-gv))) * u[r];
          Hout[(size_t)(row_start + rl) * I_ + bn * 128 + wc * 64 + n * 16 + lr] = f2bf(hv);
        }
      }
    }
}

// =====================================================================
// GEMM2: Hin [T][I] bf16 x W2T [E][H][I] bf16 -> Out [T][H] f32
// block tile 128 x 256 cols; 4 waves 2x2, wave tile 64 x 128; counted-vmcnt dbuf.
// grid 256 = 4 bn x 64 ty.
// =====================================================================
__launch_bounds__(256, 2)
__global__ void gemm2(const unsigned short* __restrict__ Hin,
                      const unsigned short* __restrict__ W2T,
                      const int* __restrict__ counts,
                      float* __restrict__ Out) {
  __shared__ unsigned short As[2][BM * BK];
  __shared__ unsigned short Bs[2][256 * BK];
  int id = blockIdx.x;
  int swz = (id & 7) * 32 + (id >> 3);             // 256 % 8 == 0
  int bn = swz & 3;                                // output col block (256 wide)
  int tyid = swz >> 2;
  int row_start, rows, expert;
  find_tile(counts, tyid, row_start, rows, expert);
  int tid = threadIdx.x, wid = tid >> 6, lane = tid & 63;
  int wr = wid >> 1, wc = wid & 1;
  const unsigned short* Wp = W2T + (size_t)expert * H_ * I_;

  f32x4 acc[4][8];
  #pragma unroll
  for (int m = 0; m < 4; ++m)
    #pragma unroll
    for (int n = 0; n < 8; ++n) acc[m][n] = {0.f, 0.f, 0.f, 0.f};

  int l4 = lane >> 2;
  int csw = ((lane & 3) ^ ((l4 >> 1) & 3)) * 8;
  int lr = lane & 15;
  int ck = ((lane >> 4) ^ ((lr >> 1) & 3)) * 8;

#define STAGE2(buf, kt) do {                                                   \
    int k0 = (kt) * BK + csw;                                                  \
    _Pragma("unroll")                                                          \
    for (int i = 0; i < 2; ++i) {                                              \
      int r = wid * 32 + i * 16;                                               \
      int gr = row_start + min(r + l4, rows - 1);                              \
      gload_lds16(Hin + (size_t)gr * I_ + k0, &As[buf][r * BK]);               \
    }                                                                          \
    _Pragma("unroll")                                                          \
    for (int i = 0; i < 4; ++i) {                                              \
      int r = wid * 64 + i * 16;                                               \
      int gn = bn * 256 + r + l4;                                              \
      gload_lds16(Wp + (size_t)gn * I_ + k0, &Bs[buf][r * BK]);                \
    }                                                                          \
  } while (0)

  STAGE2(0, 0);
  int cur = 0;
  for (int kt = 0; kt < NKT; ++kt) {
    STAGE2(cur ^ 1, min(kt + 1, NKT - 1));
    asm volatile("s_waitcnt vmcnt(6)" ::: "memory");
    __builtin_amdgcn_sched_barrier(0);
    __builtin_amdgcn_s_barrier();
    bf16x8 a[4], b[8];
    #pragma unroll
    for (int m = 0; m < 4; ++m)
      a[m] = *reinterpret_cast<const bf16x8*>(&As[cur][(wr * 64 + m * 16 + lr) * BK + ck]);
    #pragma unroll
    for (int n = 0; n < 8; ++n)
      b[n] = *reinterpret_cast<const bf16x8*>(&Bs[cur][(wc * 128 + n * 16 + lr) * BK + ck]);
    __builtin_amdgcn_s_setprio(1);
    #pragma unroll
    for (int m = 0; m < 4; ++m)
      #pragma unroll
      for (int n = 0; n < 8; ++n)
        acc[m][n] = __builtin_amdgcn_mfma_f32_16x16x32_bf16(a[m], b[n], acc[m][n], 0, 0, 0);
    __builtin_amdgcn_s_setprio(0);
    __builtin_amdgcn_sched_barrier(0);
    __builtin_amdgcn_s_barrier();
    cur ^= 1;
  }
#undef STAGE2

  int lq = lane >> 4;
  #pragma unroll
  for (int m = 0; m < 4; ++m)
    #pragma unroll
    for (int n = 0; n < 8; ++n)
      #pragma unroll
      for (int r = 0; r < 4; ++r) {
        int rl = wr * 64 + m * 16 + lq * 4 + r;
        if (rl < rows)
          Out[(size_t)(row_start + rl) * H_ + bn * 256 + wc * 128 + n * 16 + lr] =
              acc[m][n][r];
      }
}

extern "C" void kernel_launch(void* const* d_in, const int* in_sizes, int n_in,
                              void* d_out, int out_size, void* d_ws, size_t ws_size,
                              hipStream_t stream) {
  const float* x  = (const float*)d_in[0];
  const float* w1 = (const float*)d_in[1];   // [E][H][2I]
  const float* w2 = (const float*)d_in[2];   // [E][I][H]
  const int* counts = (const int*)d_in[3];
  float* out = (float*)d_out;

  char* ws = (char*)d_ws;
  unsigned short* xb  = (unsigned short*)ws;
  unsigned short* w1t = (unsigned short*)(ws + (size_t)T_ * H_ * 2);
  unsigned short* w2t = (unsigned short*)(ws + (size_t)T_ * H_ * 2
                                             + (size_t)E_ * 2 * I_ * H_ * 2);
  unsigned short* hbuf = (unsigned short*)(ws + (size_t)T_ * H_ * 2
                                              + (size_t)E_ * 2 * I_ * H_ * 2
                                              + (size_t)E_ * H_ * I_ * 2);

  convert_f32_bf16<<<(T_ * H_) / 1024, 256, 0, stream>>>(x, xb, T_ * H_);
  dim3 tb(32, 8);
  transpose_f32_to_bf16<<<dim3((2 * I_) / 32, H_ / 64, E_), tb, 0, stream>>>(w1, w1t, H_, 2 * I_);
  transpose_f32_to_bf16<<<dim3(H_ / 32, I_ / 64, E_), tb, 0, stream>>>(w2, w2t, I_, H_);
  gemm1_swiglu<<<512, 256, 0, stream>>>(xb, w1t, counts, hbuf);
  gemm2<<<256, 256, 0, stream>>>(hbuf, w2t, counts, out);
}

// Round 4
// 118.088 us; speedup vs baseline: 1.1472x; 1.0196x over previous
//
#include <hip/hip_runtime.h>
#include <hip/hip_bf16.h>
#include <stdint.h>

#define E_ 8
#define H_ 1024
#define I_ 1024
#define T_ 8192
#define BM 128
#define BK 32
#define NKT 32               // K/BK for both GEMMs

typedef __attribute__((ext_vector_type(4))) float f32x4;
typedef __attribute__((ext_vector_type(8))) short bf16x8;

__device__ __forceinline__ unsigned short f2bf(float f) {
  union { float f; unsigned int u; } v; v.f = f;
  unsigned int lsb = (v.u >> 16) & 1u;
  v.u += 0x7fffu + lsb;
  return (unsigned short)(v.u >> 16);
}

__device__ __forceinline__ void gload_lds16(const void* g, void* l) {
  __builtin_amdgcn_global_load_lds(
      (const __attribute__((address_space(1))) unsigned int*)g,
      (__attribute__((address_space(3))) unsigned int*)l,
      16, 0, 0);
}

// ---------------- conversion: f32 -> bf16 ----------------
__global__ void convert_f32_bf16(const float* __restrict__ in,
                                 unsigned short* __restrict__ out, int n) {
  int i = (blockIdx.x * blockDim.x + threadIdx.x) * 4;
  if (i >= n) return;
  float4 v = *reinterpret_cast<const float4*>(in + i);
  ushort4 o;
  o.x = f2bf(v.x); o.y = f2bf(v.y); o.z = f2bf(v.z); o.w = f2bf(v.w);
  *reinterpret_cast<ushort4*>(out + i) = o;
}

// ------------- transpose+convert: [E][R][C] f32 -> [E][C][R] bf16 -------------
__global__ void transpose_f32_to_bf16(const float* __restrict__ in,
                                      unsigned short* __restrict__ out,
                                      int R, int C) {
  __shared__ float tile[64][33];
  int e = blockIdx.z;
  const float* inp = in + (size_t)e * R * C;
  unsigned short* outp = out + (size_t)e * R * C;
  int c0 = blockIdx.x * 32, r0 = blockIdx.y * 64;
  int tx = threadIdx.x, ty = threadIdx.y;      // 32 x 8
  for (int rr = ty; rr < 64; rr += 8)
    tile[rr][tx] = inp[(size_t)(r0 + rr) * C + c0 + tx];
  __syncthreads();
  for (int cc = ty; cc < 32; cc += 8) {
    ushort2 o;
    o.x = f2bf(tile[2 * tx][cc]);
    o.y = f2bf(tile[2 * tx + 1][cc]);
    *reinterpret_cast<ushort2*>(&outp[(size_t)(c0 + cc) * R + r0 + 2 * tx]) = o;
  }
}

// ------------- expert lookup -------------
__device__ __forceinline__ void find_tile(const int* counts, int ty,
                                          int& row_start, int& rows, int& expert) {
  int tacc = 0, off = 0;
  expert = 0; row_start = 0; rows = BM;
  #pragma unroll
  for (int e = 0; e < E_; ++e) {
    int c = counts[e];
    int te = (c + BM - 1) >> 7;
    if (ty >= tacc && ty < tacc + te) {
      expert = e;
      int lt = ty - tacc;
      row_start = off + lt * BM;
      rows = min(BM, c - lt * BM);
    }
    tacc += te; off += c;
  }
}

// =====================================================================
// GEMM1 + SwiGLU: X [T][H] bf16 x W1T [E][2I][H] bf16 -> Hout [T][I] bf16
// block 128 rows x 64 h-cols (B rows: 64 gate + 64 up). 4 waves 2x2,
// wave 64 x 32 h (acc[4][2 gate + 2 up]); BK=32; counted-vmcnt dbuf.
// grid 1024 = 16 bn x 64 ty, XCD-swizzled; 4 blocks/CU.
// =====================================================================
__launch_bounds__(256, 4)
__global__ void gemm1_swiglu(const unsigned short* __restrict__ X,
                             const unsigned short* __restrict__ W1T,
                             const int* __restrict__ counts,
                             unsigned short* __restrict__ Hout) {
  __shared__ unsigned short As[2][BM * BK];        // 128 x 32
  __shared__ unsigned short Bs[2][128 * BK];       // 128 x 32 (64 gate + 64 up)
  int id = blockIdx.x;
  int swz = (id & 7) * 128 + (id >> 3);            // 1024 % 8 == 0, bijective
  int bn = swz & 15;                               // h block (64 wide)
  int tyid = swz >> 4;                             // M tile 0..63
  int row_start, rows, expert;
  find_tile(counts, tyid, row_start, rows, expert);
  int tid = threadIdx.x, wid = tid >> 6, lane = tid & 63;
  int wr = wid >> 1, wc = wid & 1;
  const unsigned short* Wp = W1T + (size_t)expert * (2 * I_) * H_;

  f32x4 acc[4][4];
  #pragma unroll
  for (int m = 0; m < 4; ++m)
    #pragma unroll
    for (int n = 0; n < 4; ++n) acc[m][n] = {0.f, 0.f, 0.f, 0.f};

  int l4 = lane >> 2;
  int csw = ((lane & 3) ^ ((l4 >> 1) & 3)) * 8;    // pre-swizzled global k-chunk
  int lr = lane & 15;
  int ck = ((lane >> 4) ^ ((lr >> 1) & 3)) * 8;    // swizzled ds_read k-chunk

  // B LDS row r: r<64 -> gate col bn*64+r ; r>=64 -> up col I_ + bn*64 + (r-64)
#define B1ROW(r) (((r) < 64) ? (bn * 64 + (r)) : (I_ + bn * 64 + ((r) - 64)))

  // per-wave: 2 A groups + 2 B groups = 4 gload_lds
#define STAGE1(buf, kt) do {                                                   \
    int k0 = (kt) * BK + csw;                                                  \
    _Pragma("unroll")                                                          \
    for (int i = 0; i < 2; ++i) {                                              \
      int r = wid * 32 + i * 16;                                               \
      int gr = row_start + min(r + l4, rows - 1);                              \
      gload_lds16(X + (size_t)gr * H_ + k0, &As[buf][r * BK]);                 \
    }                                                                          \
    _Pragma("unroll")                                                          \
    for (int i = 0; i < 2; ++i) {                                              \
      int r = wid * 32 + i * 16;                                               \
      int gn = B1ROW(r + l4);                                                  \
      gload_lds16(Wp + (size_t)gn * H_ + k0, &Bs[buf][r * BK]);                \
    }                                                                          \
  } while (0)

  STAGE1(0, 0);
  int cur = 0;
  for (int kt = 0; kt < NKT; ++kt) {
    STAGE1(cur ^ 1, min(kt + 1, NKT - 1));
    asm volatile("s_waitcnt vmcnt(4)" ::: "memory");
    __builtin_amdgcn_sched_barrier(0);
    __builtin_amdgcn_s_barrier();
    bf16x8 a[4], b[4];
    #pragma unroll
    for (int m = 0; m < 4; ++m)
      a[m] = *reinterpret_cast<const bf16x8*>(&As[cur][(wr * 64 + m * 16 + lr) * BK + ck]);
    #pragma unroll
    for (int n = 0; n < 2; ++n) {
      b[n]     = *reinterpret_cast<const bf16x8*>(&Bs[cur][(wc * 32 + n * 16 + lr) * BK + ck]);
      b[n + 2] = *reinterpret_cast<const bf16x8*>(&Bs[cur][(64 + wc * 32 + n * 16 + lr) * BK + ck]);
    }
    __builtin_amdgcn_s_setprio(1);
    #pragma unroll
    for (int m = 0; m < 4; ++m)
      #pragma unroll
      for (int n = 0; n < 4; ++n)
        acc[m][n] = __builtin_amdgcn_mfma_f32_16x16x32_bf16(a[m], b[n], acc[m][n], 0, 0, 0);
    __builtin_amdgcn_s_setprio(0);
    __builtin_amdgcn_sched_barrier(0);
    __builtin_amdgcn_s_barrier();
    cur ^= 1;
  }
#undef STAGE1
#undef B1ROW

  int lq = lane >> 4;
  #pragma unroll
  for (int m = 0; m < 4; ++m)
    #pragma unroll
    for (int n = 0; n < 2; ++n) {
      f32x4 g = acc[m][n], u = acc[m][n + 2];
      #pragma unroll
      for (int r = 0; r < 4; ++r) {
        int rl = wr * 64 + m * 16 + lq * 4 + r;
        if (rl < rows) {
          float gv = g[r];
          float hv = (gv / (1.f + __expf(-gv))) * u[r];
          Hout[(size_t)(row_start + rl) * I_ + bn * 64 + wc * 32 + n * 16 + lr] = f2bf(hv);
        }
      }
    }
}

// =====================================================================
// GEMM2: Hin [T][I] bf16 x W2T [E][H][I] bf16 -> Out [T][H] f32
// block 128 x 64 cols; 4 waves 2x2, wave 64 x 32 (acc[4][2]).
// grid 1024 = 16 bn x 64 ty; 4 blocks/CU.
// =====================================================================
__launch_bounds__(256, 4)
__global__ void gemm2(const unsigned short* __restrict__ Hin,
                      const unsigned short* __restrict__ W2T,
                      const int* __restrict__ counts,
                      float* __restrict__ Out) {
  __shared__ unsigned short As[2][BM * BK];
  __shared__ unsigned short Bs[2][64 * BK];
  int id = blockIdx.x;
  int swz = (id & 7) * 128 + (id >> 3);
  int bn = swz & 15;                               // out col block (64 wide)
  int tyid = swz >> 4;
  int row_start, rows, expert;
  find_tile(counts, tyid, row_start, rows, expert);
  int tid = threadIdx.x, wid = tid >> 6, lane = tid & 63;
  int wr = wid >> 1, wc = wid & 1;
  const unsigned short* Wp = W2T + (size_t)expert * H_ * I_;

  f32x4 acc[4][2];
  #pragma unroll
  for (int m = 0; m < 4; ++m)
    #pragma unroll
    for (int n = 0; n < 2; ++n) acc[m][n] = {0.f, 0.f, 0.f, 0.f};

  int l4 = lane >> 2;
  int csw = ((lane & 3) ^ ((l4 >> 1) & 3)) * 8;
  int lr = lane & 15;
  int ck = ((lane >> 4) ^ ((lr >> 1) & 3)) * 8;

  // per-wave: 2 A groups + 1 B group (64 rows / 4 waves = 16) = 3 gload_lds
#define STAGE2(buf, kt) do {                                                   \
    int k0 = (kt) * BK + csw;                                                  \
    _Pragma("unroll")                                                          \
    for (int i = 0; i < 2; ++i) {                                              \
      int r = wid * 32 + i * 16;                                               \
      int gr = row_start + min(r + l4, rows - 1);                              \
      gload_lds16(Hin + (size_t)gr * I_ + k0, &As[buf][r * BK]);               \
    }                                                                          \
    {                                                                          \
      int r = wid * 16;                                                        \
      int gn = bn * 64 + r + l4;                                               \
      gload_lds16(Wp + (size_t)gn * I_ + k0, &Bs[buf][r * BK]);                \
    }                                                                          \
  } while (0)

  STAGE2(0, 0);
  int cur = 0;
  for (int kt = 0; kt < NKT; ++kt) {
    STAGE2(cur ^ 1, min(kt + 1, NKT - 1));
    asm volatile("s_waitcnt vmcnt(3)" ::: "memory");
    __builtin_amdgcn_sched_barrier(0);
    __builtin_amdgcn_s_barrier();
    bf16x8 a[4], b[2];
    #pragma unroll
    for (int m = 0; m < 4; ++m)
      a[m] = *reinterpret_cast<const bf16x8*>(&As[cur][(wr * 64 + m * 16 + lr) * BK + ck]);
    #pragma unroll
    for (int n = 0; n < 2; ++n)
      b[n] = *reinterpret_cast<const bf16x8*>(&Bs[cur][(wc * 32 + n * 16 + lr) * BK + ck]);
    __builtin_amdgcn_s_setprio(1);
    #pragma unroll
    for (int m = 0; m < 4; ++m)
      #pragma unroll
      for (int n = 0; n < 2; ++n)
        acc[m][n] = __builtin_amdgcn_mfma_f32_16x16x32_bf16(a[m], b[n], acc[m][n], 0, 0, 0);
    __builtin_amdgcn_s_setprio(0);
    __builtin_amdgcn_sched_barrier(0);
    __builtin_amdgcn_s_barrier();
    cur ^= 1;
  }
#undef STAGE2

  int lq = lane >> 4;
  #pragma unroll
  for (int m = 0; m < 4; ++m)
    #pragma unroll
    for (int n = 0; n < 2; ++n)
      #pragma unroll
      for (int r = 0; r < 4; ++r) {
        int rl = wr * 64 + m * 16 + lq * 4 + r;
        if (rl < rows)
          Out[(size_t)(row_start + rl) * H_ + bn * 64 + wc * 32 + n * 16 + lr] =
              acc[m][n][r];
      }
}

extern "C" void kernel_launch(void* const* d_in, const int* in_sizes, int n_in,
                              void* d_out, int out_size, void* d_ws, size_t ws_size,
                              hipStream_t stream) {
  const float* x  = (const float*)d_in[0];
  const float* w1 = (const float*)d_in[1];   // [E][H][2I]
  const float* w2 = (const float*)d_in[2];   // [E][I][H]
  const int* counts = (const int*)d_in[3];
  float* out = (float*)d_out;

  char* ws = (char*)d_ws;
  unsigned short* xb  = (unsigned short*)ws;
  unsigned short* w1t = (unsigned short*)(ws + (size_t)T_ * H_ * 2);
  unsigned short* w2t = (unsigned short*)(ws + (size_t)T_ * H_ * 2
                                             + (size_t)E_ * 2 * I_ * H_ * 2);
  unsigned short* hbuf = (unsigned short*)(ws + (size_t)T_ * H_ * 2
                                              + (size_t)E_ * 2 * I_ * H_ * 2
                                              + (size_t)E_ * H_ * I_ * 2);

  convert_f32_bf16<<<(T_ * H_) / 1024, 256, 0, stream>>>(x, xb, T_ * H_);
  dim3 tb(32, 8);
  transpose_f32_to_bf16<<<dim3((2 * I_) / 32, H_ / 64, E_), tb, 0, stream>>>(w1, w1t, H_, 2 * I_);
  transpose_f32_to_bf16<<<dim3(H_ / 32, I_ / 64, E_), tb, 0, stream>>>(w2, w2t, I_, H_);
  gemm1_swiglu<<<1024, 256, 0, stream>>>(xb, w1t, counts, hbuf);
  gemm2<<<1024, 256, 0, stream>>>(hbuf, w2t, counts, out);
}

// Round 5
// 108.951 us; speedup vs baseline: 1.2434x; 1.0839x over previous
//
#include <hip/hip_runtime.h>
#include <hip/hip_bf16.h>
#include <stdint.h>

#define E_ 8
#define H_ 1024
#define I_ 1024
#define T_ 8192
#define BM 128
#define BK 32
#define NKT 32

typedef __attribute__((ext_vector_type(4))) float f32x4;
typedef __attribute__((ext_vector_type(8))) short bf16x8;

__device__ __forceinline__ unsigned short f2bf(float f) {
  union { float f; unsigned int u; } v; v.f = f;
  unsigned int lsb = (v.u >> 16) & 1u;
  v.u += 0x7fffu + lsb;          // RNE
  return (unsigned short)(v.u >> 16);
}

__device__ __forceinline__ void gload_lds16(const void* g, void* l) {
  __builtin_amdgcn_global_load_lds(
      (const __attribute__((address_space(1))) unsigned int*)g,
      (__attribute__((address_space(3))) unsigned int*)l,
      16, 0, 0);
}

// ------------- expert lookup -------------
__device__ __forceinline__ void find_tile(const int* counts, int ty,
                                          int& row_start, int& rows, int& expert) {
  int tacc = 0, off = 0;
  expert = 0; row_start = 0; rows = BM;
  #pragma unroll
  for (int e = 0; e < E_; ++e) {
    int c = counts[e];
    int te = (c + BM - 1) >> 7;
    if (ty >= tacc && ty < tacc + te) {
      expert = e;
      int lt = ty - tacc;
      row_start = off + lt * BM;
      rows = min(BM, c - lt * BM);
    }
    tacc += te; off += c;
  }
}

// ---------- transpose role (shared by both union kernels) ----------
// [R][C] f32 -> [C][R] bf16, 64-row x 32-col input tile, smem >= 64*33*4 B
__device__ __forceinline__ void transpose_role(const float* inp,
                                               unsigned short* outp,
                                               int R, int C, int bx, int by,
                                               void* smem) {
  float (*tile)[33] = reinterpret_cast<float(*)[33]>(smem);
  int c0 = bx * 32, r0 = by * 64;
  int tx = threadIdx.x & 31, ty = threadIdx.x >> 5;   // 32 x 8
  for (int rr = ty; rr < 64; rr += 8)
    tile[rr][tx] = inp[(size_t)(r0 + rr) * C + c0 + tx];
  __syncthreads();
  for (int cc = ty; cc < 32; cc += 8) {
    ushort2 o;
    o.x = f2bf(tile[2 * tx][cc]);
    o.y = f2bf(tile[2 * tx + 1][cc]);
    *reinterpret_cast<ushort2*>(&outp[(size_t)(c0 + cc) * R + r0 + 2 * tx]) = o;
  }
}

// =====================================================================
// preproc_union: blocks [0,8192) convert x f32->bf16; [8192,16384) transpose w1
// =====================================================================
__global__ __launch_bounds__(256) void preproc_union(
    const float* __restrict__ x, unsigned short* __restrict__ xb,
    const float* __restrict__ w1, unsigned short* __restrict__ w1t) {
  __shared__ float tile[64][33];
  int id = blockIdx.x;
  if (id < 8192) {
    int i = (id * 256 + threadIdx.x) * 4;
    float4 v = *reinterpret_cast<const float4*>(x + i);
    ushort4 o;
    o.x = f2bf(v.x); o.y = f2bf(v.y); o.z = f2bf(v.z); o.w = f2bf(v.w);
    *reinterpret_cast<ushort4*>(xb + i) = o;
    return;
  }
  int tb = id - 8192;                       // w1: R=H_, C=2I -> grid 64 x 16 x 8
  int bx = tb & 63, by = (tb >> 6) & 15, bz = tb >> 10;
  transpose_role(w1 + (size_t)bz * H_ * 2 * I_,
                 w1t + (size_t)bz * H_ * 2 * I_, H_, 2 * I_, bx, by, tile);
}

// =====================================================================
// gemm1_union: blocks [0,4096) transpose w2; [4096, 4608) grouped GEMM1+SwiGLU
// GEMM1: X [T][H] bf16 x W1T [E][2I][H] bf16 -> Hout [T][I] bf16
// block: 128 rows x 256 B-rows (per wave: 32 gate + 32 up cols, interleaved)
// 4 waves (1m x 4n), wave tile 128 x 64, acc[8][4]; BK=32; 3-buffer ring,
// vmcnt(12) = 2 tiles in flight. grid 512 = 8 bn x 64 ty, XCD-swizzled.
// =====================================================================
#define G1LDS (BM * BK + 256 * BK)          // shorts per buffer (A 8KB + B 16KB)
__global__ __launch_bounds__(256, 2) void gemm1_union(
    const unsigned short* __restrict__ X,
    const unsigned short* __restrict__ W1T,
    const int* __restrict__ counts,
    unsigned short* __restrict__ Hout,
    const float* __restrict__ w2, unsigned short* __restrict__ w2t) {
  __shared__ unsigned short pool[3 * G1LDS];  // 72 KB
  if (blockIdx.x < 4096) {
    // w2: [E][I][H] f32 -> w2t [E][H][I] bf16 ; R=I_, C=H_ -> grid 32 x 16 x 8
    int tb = blockIdx.x;
    int bx = tb & 31, by = (tb >> 5) & 15, bz = tb >> 9;
    transpose_role(w2 + (size_t)bz * I_ * H_,
                   w2t + (size_t)bz * I_ * H_, I_, H_, bx, by, pool);
    return;
  }
  int id = blockIdx.x - 4096;
  int swz = (id & 7) * 64 + (id >> 3);      // 512 % 8 == 0, bijective
  int bn = swz & 7;                          // h block (128 wide)
  int tyid = swz >> 3;                       // M tile 0..63
  int row_start, rows, expert;
  find_tile(counts, tyid, row_start, rows, expert);
  int tid = threadIdx.x, wid = tid >> 6, lane = tid & 63;
  const unsigned short* Wp = W1T + (size_t)expert * (2 * I_) * H_;

  f32x4 acc[8][4];
  #pragma unroll
  for (int m = 0; m < 8; ++m)
    #pragma unroll
    for (int n = 0; n < 4; ++n) acc[m][n] = {0.f, 0.f, 0.f, 0.f};

  int l4 = lane >> 2;
  int csw = ((lane & 3) ^ ((l4 >> 1) & 3)) * 8;   // pre-swizzled global k-chunk
  int lr = lane & 15;
  int ck = ((lane >> 4) ^ ((lr >> 1) & 3)) * 8;   // swizzled ds_read k-chunk

  // per-thread: 2 A + 4 B = 6 gload_lds per tile
#define STAGE1(buf, kt) do {                                                   \
    int k0 = (kt) * BK + csw;                                                  \
    unsigned short* Ab = pool + (buf) * G1LDS;                                 \
    unsigned short* Bb = Ab + BM * BK;                                         \
    _Pragma("unroll")                                                          \
    for (int i = 0; i < 2; ++i) {                                              \
      int r = wid * 32 + i * 16;                                               \
      int gr = row_start + min(r + l4, rows - 1);                              \
      gload_lds16(X + (size_t)gr * H_ + k0, Ab + r * BK);                      \
    }                                                                          \
    _Pragma("unroll")                                                          \
    for (int i = 0; i < 4; ++i) {                                              \
      int r = wid * 64 + i * 16;                                               \
      int rb = r + l4;                                                         \
      int sub = rb & 63, ow = rb >> 6;                                         \
      int col = (sub < 32) ? (bn * 128 + ow * 32 + sub)                        \
                           : (I_ + bn * 128 + ow * 32 + sub - 32);             \
      gload_lds16(Wp + (size_t)col * H_ + k0, Bb + r * BK);                    \
    }                                                                          \
  } while (0)

  STAGE1(0, 0);
  STAGE1(1, 1);
  for (int kt = 0; kt < NKT; ++kt) {
    STAGE1((kt + 2) % 3, min(kt + 2, NKT - 1));
    asm volatile("s_waitcnt vmcnt(12)" ::: "memory");
    __builtin_amdgcn_sched_barrier(0);
    __builtin_amdgcn_s_barrier();
    const unsigned short* Ab = pool + (kt % 3) * G1LDS;
    const unsigned short* Bb = Ab + BM * BK;
    bf16x8 a[8], b[4];
    #pragma unroll
    for (int m = 0; m < 8; ++m)
      a[m] = *reinterpret_cast<const bf16x8*>(&Ab[(m * 16 + lr) * BK + ck]);
    #pragma unroll
    for (int n = 0; n < 4; ++n)
      b[n] = *reinterpret_cast<const bf16x8*>(&Bb[(wid * 64 + n * 16 + lr) * BK + ck]);
    __builtin_amdgcn_s_setprio(1);
    #pragma unroll
    for (int m = 0; m < 8; ++m)
      #pragma unroll
      for (int n = 0; n < 4; ++n)
        acc[m][n] = __builtin_amdgcn_mfma_f32_16x16x32_bf16(a[m], b[n], acc[m][n], 0, 0, 0);
    __builtin_amdgcn_s_setprio(0);
    __builtin_amdgcn_sched_barrier(0);
    __builtin_amdgcn_s_barrier();
  }
#undef STAGE1

  int lq = lane >> 4;
  #pragma unroll
  for (int m = 0; m < 8; ++m)
    #pragma unroll
    for (int n = 0; n < 2; ++n) {
      f32x4 g = acc[m][n], u = acc[m][n + 2];
      #pragma unroll
      for (int r = 0; r < 4; ++r) {
        int rl = m * 16 + lq * 4 + r;
        if (rl < rows) {
          float gv = g[r];
          float hv = (gv / (1.f + __expf(-gv))) * u[r];
          Hout[(size_t)(row_start + rl) * I_ + bn * 128 + wid * 32 + n * 16 + lr] = f2bf(hv);
        }
      }
    }
}

// =====================================================================
// GEMM2: Hin [T][I] bf16 x W2T [E][H][I] bf16 -> Out [T][H] f32
// block 128 x 128; 4 waves 2x2, wave 64x64, acc[4][4]; BK=32; 3-buffer ring,
// vmcnt(8). grid 512 = 8 bn x 64 ty.
// =====================================================================
#define G2LDS (BM * BK + BM * BK)
__global__ __launch_bounds__(256, 3) void gemm2(
    const unsigned short* __restrict__ Hin,
    const unsigned short* __restrict__ W2T,
    const int* __restrict__ counts,
    float* __restrict__ Out) {
  __shared__ unsigned short pool[3 * G2LDS];  // 48 KB
  int id = blockIdx.x;
  int swz = (id & 7) * 64 + (id >> 3);
  int bn = swz & 7;                           // out col block (128 wide)
  int tyid = swz >> 3;
  int row_start, rows, expert;
  find_tile(counts, tyid, row_start, rows, expert);
  int tid = threadIdx.x, wid = tid >> 6, lane = tid & 63;
  int wr = wid >> 1, wc = wid & 1;
  const unsigned short* Wp = W2T + (size_t)expert * H_ * I_;

  f32x4 acc[4][4];
  #pragma unroll
  for (int m = 0; m < 4; ++m)
    #pragma unroll
    for (int n = 0; n < 4; ++n) acc[m][n] = {0.f, 0.f, 0.f, 0.f};

  int l4 = lane >> 2;
  int csw = ((lane & 3) ^ ((l4 >> 1) & 3)) * 8;
  int lr = lane & 15;
  int ck = ((lane >> 4) ^ ((lr >> 1) & 3)) * 8;

  // per-thread: 2 A + 2 B = 4 gload_lds per tile
#define STAGE2(buf, kt) do {                                                   \
    int k0 = (kt) * BK + csw;                                                  \
    unsigned short* Ab = pool + (buf) * G2LDS;                                 \
    unsigned short* Bb = Ab + BM * BK;                                         \
    _Pragma("unroll")                                                          \
    for (int i = 0; i < 2; ++i) {                                              \
      int r = wid * 32 + i * 16;                                               \
      int gr = row_start + min(r + l4, rows - 1);                              \
      gload_lds16(Hin + (size_t)gr * I_ + k0, Ab + r * BK);                    \
    }                                                                          \
    _Pragma("unroll")                                                          \
    for (int i = 0; i < 2; ++i) {                                              \
      int r = wid * 32 + i * 16;                                               \
      int col = bn * 128 + r + l4;                                             \
      gload_lds16(Wp + (size_t)col * I_ + k0, Bb + r * BK);                    \
    }                                                                          \
  } while (0)

  STAGE2(0, 0);
  STAGE2(1, 1);
  for (int kt = 0; kt < NKT; ++kt) {
    STAGE2((kt + 2) % 3, min(kt + 2, NKT - 1));
    asm volatile("s_waitcnt vmcnt(8)" ::: "memory");
    __builtin_amdgcn_sched_barrier(0);
    __builtin_amdgcn_s_barrier();
    const unsigned short* Ab = pool + (kt % 3) * G2LDS;
    const unsigned short* Bb = Ab + BM * BK;
    bf16x8 a[4], b[4];
    #pragma unroll
    for (int m = 0; m < 4; ++m)
      a[m] = *reinterpret_cast<const bf16x8*>(&Ab[(wr * 64 + m * 16 + lr) * BK + ck]);
    #pragma unroll
    for (int n = 0; n < 4; ++n)
      b[n] = *reinterpret_cast<const bf16x8*>(&Bb[(wc * 64 + n * 16 + lr) * BK + ck]);
    __builtin_amdgcn_s_setprio(1);
    #pragma unroll
    for (int m = 0; m < 4; ++m)
      #pragma unroll
      for (int n = 0; n < 4; ++n)
        acc[m][n] = __builtin_amdgcn_mfma_f32_16x16x32_bf16(a[m], b[n], acc[m][n], 0, 0, 0);
    __builtin_amdgcn_s_setprio(0);
    __builtin_amdgcn_sched_barrier(0);
    __builtin_amdgcn_s_barrier();
  }
#undef STAGE2

  int lq = lane >> 4;
  #pragma unroll
  for (int m = 0; m < 4; ++m)
    #pragma unroll
    for (int n = 0; n < 4; ++n)
      #pragma unroll
      for (int r = 0; r < 4; ++r) {
        int rl = wr * 64 + m * 16 + lq * 4 + r;
        if (rl < rows)
          Out[(size_t)(row_start + rl) * H_ + bn * 128 + wc * 64 + n * 16 + lr] =
              acc[m][n][r];
      }
}

extern "C" void kernel_launch(void* const* d_in, const int* in_sizes, int n_in,
                              void* d_out, int out_size, void* d_ws, size_t ws_size,
                              hipStream_t stream) {
  const float* x  = (const float*)d_in[0];
  const float* w1 = (const float*)d_in[1];   // [E][H][2I]
  const float* w2 = (const float*)d_in[2];   // [E][I][H]
  const int* counts = (const int*)d_in[3];
  float* out = (float*)d_out;

  char* ws = (char*)d_ws;
  unsigned short* xb  = (unsigned short*)ws;
  unsigned short* w1t = (unsigned short*)(ws + (size_t)T_ * H_ * 2);
  unsigned short* w2t = (unsigned short*)(ws + (size_t)T_ * H_ * 2
                                             + (size_t)E_ * 2 * I_ * H_ * 2);
  unsigned short* hbuf = (unsigned short*)(ws + (size_t)T_ * H_ * 2
                                              + (size_t)E_ * 2 * I_ * H_ * 2
                                              + (size_t)E_ * H_ * I_ * 2);

  // 1) convert x  ||  transpose+convert w1
  preproc_union<<<16384, 256, 0, stream>>>(x, xb, w1, w1t);
  // 2) transpose w2 (hidden)  ||  grouped GEMM1 + SwiGLU
  gemm1_union<<<4096 + 512, 256, 0, stream>>>(xb, w1t, counts, hbuf, w2, w2t);
  // 3) grouped GEMM2
  gemm2<<<512, 256, 0, stream>>>(hbuf, w2t, counts, out);
}

// Round 6
// 108.113 us; speedup vs baseline: 1.2530x; 1.0077x over previous
//
#include <hip/hip_runtime.h>
#include <hip/hip_bf16.h>
#include <stdint.h>

#define E_ 8
#define H_ 1024
#define I_ 1024
#define T_ 8192
#define BM 128
#define BK 32
#define NKT 32

typedef __attribute__((ext_vector_type(4))) float f32x4;
typedef __attribute__((ext_vector_type(8))) short bf16x8;

__device__ __forceinline__ unsigned short f2bf(float f) {
  union { float f; unsigned int u; } v; v.f = f;
  unsigned int lsb = (v.u >> 16) & 1u;
  v.u += 0x7fffu + lsb;          // RNE
  return (unsigned short)(v.u >> 16);
}

__device__ __forceinline__ void gload_lds16(const void* g, void* l) {
  __builtin_amdgcn_global_load_lds(
      (const __attribute__((address_space(1))) unsigned int*)g,
      (__attribute__((address_space(3))) unsigned int*)l,
      16, 0, 0);
}

// ------------- expert lookup -------------
__device__ __forceinline__ void find_tile(const int* counts, int ty,
                                          int& row_start, int& rows, int& expert) {
  int tacc = 0, off = 0;
  expert = 0; row_start = 0; rows = BM;
  #pragma unroll
  for (int e = 0; e < E_; ++e) {
    int c = counts[e];
    int te = (c + BM - 1) >> 7;
    if (ty >= tacc && ty < tacc + te) {
      expert = e;
      int lt = ty - tacc;
      row_start = off + lt * BM;
      rows = min(BM, c - lt * BM);
    }
    tacc += te; off += c;
  }
}

// ---------- transpose role ----------
// [R][C] f32 -> [C][R] bf16, 64-row x 32-col input tile, smem >= 64*33*4 B
__device__ __forceinline__ void transpose_role(const float* inp,
                                               unsigned short* outp,
                                               int R, int C, int bx, int by,
                                               void* smem) {
  float (*tile)[33] = reinterpret_cast<float(*)[33]>(smem);
  int c0 = bx * 32, r0 = by * 64;
  int tx = threadIdx.x & 31, ty = threadIdx.x >> 5;   // 32 x 8
  for (int rr = ty; rr < 64; rr += 8)
    tile[rr][tx] = inp[(size_t)(r0 + rr) * C + c0 + tx];
  __syncthreads();
  for (int cc = ty; cc < 32; cc += 8) {
    ushort2 o;
    o.x = f2bf(tile[2 * tx][cc]);
    o.y = f2bf(tile[2 * tx + 1][cc]);
    *reinterpret_cast<ushort2*>(&outp[(size_t)(c0 + cc) * R + r0 + 2 * tx]) = o;
  }
}

// =====================================================================
// preproc_union: blocks [0,8192) convert x f32->bf16; [8192,16384) transpose w1
// =====================================================================
__global__ __launch_bounds__(256) void preproc_union(
    const float* __restrict__ x, unsigned short* __restrict__ xb,
    const float* __restrict__ w1, unsigned short* __restrict__ w1t) {
  __shared__ float tile[64][33];
  int id = blockIdx.x;
  if (id < 8192) {
    int i = (id * 256 + threadIdx.x) * 4;
    float4 v = *reinterpret_cast<const float4*>(x + i);
    ushort4 o;
    o.x = f2bf(v.x); o.y = f2bf(v.y); o.z = f2bf(v.z); o.w = f2bf(v.w);
    *reinterpret_cast<ushort4*>(xb + i) = o;
    return;
  }
  int tb = id - 8192;                       // w1: R=H_, C=2I -> 64 x 16 x 8
  int bx = tb & 63, by = (tb >> 6) & 15, bz = tb >> 10;
  transpose_role(w1 + (size_t)bz * H_ * 2 * I_,
                 w1t + (size_t)bz * H_ * 2 * I_, H_, 2 * I_, bx, by, tile);
}

// =====================================================================
// gemm1_union: blocks [0,512) grouped GEMM1+SwiGLU; [512, 4608) transpose w2
// (GEMM FIRST so the 512 GEMM blocks own the CUs from t=0; transposes backfill)
// GEMM1: X [T][H] bf16 x W1T [E][2I][H] bf16 -> Hout [T][I] bf16
// block: 128 rows x 256 B-rows; 4 waves (1m x 4n), wave 128 x 64, acc[8][4];
// BK=32; 3-buffer ring, vmcnt(12). 512 = 8 bn x 64 ty, XCD-swizzled.
// =====================================================================
#define GLDS (BM * BK + 256 * BK)           // shorts per ring buffer (24 KB)
__global__ __launch_bounds__(256, 2) void gemm1_union(
    const unsigned short* __restrict__ X,
    const unsigned short* __restrict__ W1T,
    const int* __restrict__ counts,
    unsigned short* __restrict__ Hout,
    const float* __restrict__ w2, unsigned short* __restrict__ w2t) {
  __shared__ unsigned short pool[3 * GLDS];  // 72 KB
  if (blockIdx.x >= 512) {
    // w2: [E][I][H] f32 -> w2t [E][H][I] bf16 ; 32 x 16 x 8
    int tb = blockIdx.x - 512;
    int bx = tb & 31, by = (tb >> 5) & 15, bz = tb >> 9;
    transpose_role(w2 + (size_t)bz * I_ * H_,
                   w2t + (size_t)bz * I_ * H_, I_, H_, bx, by, pool);
    return;
  }
  int id = blockIdx.x;
  int swz = (id & 7) * 64 + (id >> 3);      // 512 % 8 == 0, bijective
  int bn = swz & 7;                          // h block (128 wide)
  int tyid = swz >> 3;                       // M tile 0..63
  int row_start, rows, expert;
  find_tile(counts, tyid, row_start, rows, expert);
  int tid = threadIdx.x, wid = tid >> 6, lane = tid & 63;
  const unsigned short* Wp = W1T + (size_t)expert * (2 * I_) * H_;

  f32x4 acc[8][4];
  #pragma unroll
  for (int m = 0; m < 8; ++m)
    #pragma unroll
    for (int n = 0; n < 4; ++n) acc[m][n] = {0.f, 0.f, 0.f, 0.f};

  int l4 = lane >> 2;
  int csw = ((lane & 3) ^ ((l4 >> 1) & 3)) * 8;   // pre-swizzled global k-chunk
  int lr = lane & 15;
  int ck = ((lane >> 4) ^ ((lr >> 1) & 3)) * 8;   // swizzled ds_read k-chunk

  // per-thread: 2 A + 4 B = 6 gload_lds per tile
#define STAGE1(buf, kt) do {                                                   \
    int k0 = (kt) * BK + csw;                                                  \
    unsigned short* Ab = pool + (buf) * GLDS;                                  \
    unsigned short* Bb = Ab + BM * BK;                                         \
    _Pragma("unroll")                                                          \
    for (int i = 0; i < 2; ++i) {                                              \
      int r = wid * 32 + i * 16;                                               \
      int gr = row_start + min(r + l4, rows - 1);                              \
      gload_lds16(X + (size_t)gr * H_ + k0, Ab + r * BK);                      \
    }                                                                          \
    _Pragma("unroll")                                                          \
    for (int i = 0; i < 4; ++i) {                                              \
      int r = wid * 64 + i * 16;                                               \
      int rb = r + l4;                                                         \
      int sub = rb & 63, ow = rb >> 6;                                         \
      int col = (sub < 32) ? (bn * 128 + ow * 32 + sub)                        \
                           : (I_ + bn * 128 + ow * 32 + sub - 32);             \
      gload_lds16(Wp + (size_t)col * H_ + k0, Bb + r * BK);                    \
    }                                                                          \
  } while (0)

  STAGE1(0, 0);
  STAGE1(1, 1);
  for (int kt = 0; kt < NKT; ++kt) {
    STAGE1((kt + 2) % 3, min(kt + 2, NKT - 1));
    asm volatile("s_waitcnt vmcnt(12)" ::: "memory");
    __builtin_amdgcn_sched_barrier(0);
    __builtin_amdgcn_s_barrier();
    const unsigned short* Ab = pool + (kt % 3) * GLDS;
    const unsigned short* Bb = Ab + BM * BK;
    bf16x8 a[8], b[4];
    #pragma unroll
    for (int m = 0; m < 8; ++m)
      a[m] = *reinterpret_cast<const bf16x8*>(&Ab[(m * 16 + lr) * BK + ck]);
    #pragma unroll
    for (int n = 0; n < 4; ++n)
      b[n] = *reinterpret_cast<const bf16x8*>(&Bb[(wid * 64 + n * 16 + lr) * BK + ck]);
    __builtin_amdgcn_s_setprio(1);
    #pragma unroll
    for (int m = 0; m < 8; ++m)
      #pragma unroll
      for (int n = 0; n < 4; ++n)
        acc[m][n] = __builtin_amdgcn_mfma_f32_16x16x32_bf16(a[m], b[n], acc[m][n], 0, 0, 0);
    __builtin_amdgcn_s_setprio(0);
    __builtin_amdgcn_s_barrier();
  }
#undef STAGE1

  int lq = lane >> 4;
  #pragma unroll
  for (int m = 0; m < 8; ++m)
    #pragma unroll
    for (int n = 0; n < 2; ++n) {
      f32x4 g = acc[m][n], u = acc[m][n + 2];
      #pragma unroll
      for (int r = 0; r < 4; ++r) {
        int rl = m * 16 + lq * 4 + r;
        if (rl < rows) {
          float gv = g[r];
          float hv = (gv / (1.f + __expf(-gv))) * u[r];
          Hout[(size_t)(row_start + rl) * I_ + bn * 128 + wid * 32 + n * 16 + lr] = f2bf(hv);
        }
      }
    }
}

// =====================================================================
// GEMM2: Hin [T][I] bf16 x W2T [E][H][I] bf16 -> Out [T][H] f32
// Same structure as gemm1: block 128 x 256, 4 waves (1m x 4n), wave 128x64,
// acc[8][4]; 3-ring, vmcnt(12). grid 256 = 4 bn x 64 ty.
// =====================================================================
__global__ __launch_bounds__(256, 2) void gemm2(
    const unsigned short* __restrict__ Hin,
    const unsigned short* __restrict__ W2T,
    const int* __restrict__ counts,
    float* __restrict__ Out) {
  __shared__ unsigned short pool[3 * GLDS];  // 72 KB
  int id = blockIdx.x;
  int swz = (id & 7) * 32 + (id >> 3);       // 256 % 8 == 0
  int bn = swz & 3;                           // out col block (256 wide)
  int tyid = swz >> 2;
  int row_start, rows, expert;
  find_tile(counts, tyid, row_start, rows, expert);
  int tid = threadIdx.x, wid = tid >> 6, lane = tid & 63;
  const unsigned short* Wp = W2T + (size_t)expert * H_ * I_;

  f32x4 acc[8][4];
  #pragma unroll
  for (int m = 0; m < 8; ++m)
    #pragma unroll
    for (int n = 0; n < 4; ++n) acc[m][n] = {0.f, 0.f, 0.f, 0.f};

  int l4 = lane >> 2;
  int csw = ((lane & 3) ^ ((l4 >> 1) & 3)) * 8;
  int lr = lane & 15;
  int ck = ((lane >> 4) ^ ((lr >> 1) & 3)) * 8;

  // per-thread: 2 A + 4 B = 6 gload_lds per tile
#define STAGE2(buf, kt) do {                                                   \
    int k0 = (kt) * BK + csw;                                                  \
    unsigned short* Ab = pool + (buf) * GLDS;                                  \
    unsigned short* Bb = Ab + BM * BK;                                         \
    _Pragma("unroll")                                                          \
    for (int i = 0; i < 2; ++i) {                                              \
      int r = wid * 32 + i * 16;                                               \
      int gr = row_start + min(r + l4, rows - 1);                              \
      gload_lds16(Hin + (size_t)gr * I_ + k0, Ab + r * BK);                    \
    }                                                                          \
    _Pragma("unroll")                                                          \
    for (int i = 0; i < 4; ++i) {                                              \
      int r = wid * 64 + i * 16;                                               \
      int col = bn * 256 + r + l4;                                             \
      gload_lds16(Wp + (size_t)col * I_ + k0, Bb + r * BK);                    \
    }                                                                          \
  } while (0)

  STAGE2(0, 0);
  STAGE2(1, 1);
  for (int kt = 0; kt < NKT; ++kt) {
    STAGE2((kt + 2) % 3, min(kt + 2, NKT - 1));
    asm volatile("s_waitcnt vmcnt(12)" ::: "memory");
    __builtin_amdgcn_sched_barrier(0);
    __builtin_amdgcn_s_barrier();
    const unsigned short* Ab = pool + (kt % 3) * GLDS;
    const unsigned short* Bb = Ab + BM * BK;
    bf16x8 a[8], b[4];
    #pragma unroll
    for (int m = 0; m < 8; ++m)
      a[m] = *reinterpret_cast<const bf16x8*>(&Ab[(m * 16 + lr) * BK + ck]);
    #pragma unroll
    for (int n = 0; n < 4; ++n)
      b[n] = *reinterpret_cast<const bf16x8*>(&Bb[(wid * 64 + n * 16 + lr) * BK + ck]);
    __builtin_amdgcn_s_setprio(1);
    #pragma unroll
    for (int m = 0; m < 8; ++m)
      #pragma unroll
      for (int n = 0; n < 4; ++n)
        acc[m][n] = __builtin_amdgcn_mfma_f32_16x16x32_bf16(a[m], b[n], acc[m][n], 0, 0, 0);
    __builtin_amdgcn_s_setprio(0);
    __builtin_amdgcn_s_barrier();
  }
#undef STAGE2

  int lq = lane >> 4;
  #pragma unroll
  for (int m = 0; m < 8; ++m)
    #pragma unroll
    for (int n = 0; n < 4; ++n)
      #pragma unroll
      for (int r = 0; r < 4; ++r) {
        int rl = m * 16 + lq * 4 + r;
        if (rl < rows)
          Out[(size_t)(row_start + rl) * H_ + bn * 256 + wid * 64 + n * 16 + lr] =
              acc[m][n][r];
      }
}

extern "C" void kernel_launch(void* const* d_in, const int* in_sizes, int n_in,
                              void* d_out, int out_size, void* d_ws, size_t ws_size,
                              hipStream_t stream) {
  const float* x  = (const float*)d_in[0];
  const float* w1 = (const float*)d_in[1];   // [E][H][2I]
  const float* w2 = (const float*)d_in[2];   // [E][I][H]
  const int* counts = (const int*)d_in[3];
  float* out = (float*)d_out;

  char* ws = (char*)d_ws;
  unsigned short* xb  = (unsigned short*)ws;
  unsigned short* w1t = (unsigned short*)(ws + (size_t)T_ * H_ * 2);
  unsigned short* w2t = (unsigned short*)(ws + (size_t)T_ * H_ * 2
                                             + (size_t)E_ * 2 * I_ * H_ * 2);
  unsigned short* hbuf = (unsigned short*)(ws + (size_t)T_ * H_ * 2
                                              + (size_t)E_ * 2 * I_ * H_ * 2
                                              + (size_t)E_ * H_ * I_ * 2);

  // 1) convert x  ||  transpose+convert w1
  preproc_union<<<16384, 256, 0, stream>>>(x, xb, w1, w1t);
  // 2) grouped GEMM1 + SwiGLU (first)  ||  transpose w2 (backfills)
  gemm1_union<<<512 + 4096, 256, 0, stream>>>(xb, w1t, counts, hbuf, w2, w2t);
  // 3) grouped GEMM2
  gemm2<<<256, 256, 0, stream>>>(hbuf, w2t, counts, out);
}

// Round 7
// 101.823 us; speedup vs baseline: 1.3304x; 1.0618x over previous
//
#include <hip/hip_runtime.h>
#include <hip/hip_bf16.h>
#include <stdint.h>

#define E_ 8
#define H_ 1024
#define I_ 1024
#define T_ 8192
#define BM 128
#define BK 32
#define NKT 32

typedef __attribute__((ext_vector_type(4))) float f32x4;
typedef __attribute__((ext_vector_type(8))) short bf16x8;

__device__ __forceinline__ unsigned short f2bf(float f) {
  union { float f; unsigned int u; } v; v.f = f;
  unsigned int lsb = (v.u >> 16) & 1u;
  v.u += 0x7fffu + lsb;          // RNE
  return (unsigned short)(v.u >> 16);
}

__device__ __forceinline__ void gload_lds16(const void* g, void* l) {
  __builtin_amdgcn_global_load_lds(
      (const __attribute__((address_space(1))) unsigned int*)g,
      (__attribute__((address_space(3))) unsigned int*)l,
      16, 0, 0);
}

// ------------- expert lookup -------------
__device__ __forceinline__ void find_tile(const int* counts, int ty,
                                          int& row_start, int& rows, int& expert) {
  int tacc = 0, off = 0;
  expert = 0; row_start = 0; rows = BM;
  #pragma unroll
  for (int e = 0; e < E_; ++e) {
    int c = counts[e];
    int te = (c + BM - 1) >> 7;
    if (ty >= tacc && ty < tacc + te) {
      expert = e;
      int lt = ty - tacc;
      row_start = off + lt * BM;
      rows = min(BM, c - lt * BM);
    }
    tacc += te; off += c;
  }
}

// ---------- transpose role ----------
// [R][C] f32 -> [C][R] bf16, 64-row x 32-col input tile
__device__ __forceinline__ void transpose_role(const float* inp,
                                               unsigned short* outp,
                                               int R, int C, int bx, int by,
                                               void* smem) {
  float (*tile)[33] = reinterpret_cast<float(*)[33]>(smem);
  int c0 = bx * 32, r0 = by * 64;
  int tx = threadIdx.x & 31, ty = threadIdx.x >> 5;   // 32 x 8
  for (int rr = ty; rr < 64; rr += 8)
    tile[rr][tx] = inp[(size_t)(r0 + rr) * C + c0 + tx];
  __syncthreads();
  for (int cc = ty; cc < 32; cc += 8) {
    ushort2 o;
    o.x = f2bf(tile[2 * tx][cc]);
    o.y = f2bf(tile[2 * tx + 1][cc]);
    *reinterpret_cast<ushort2*>(&outp[(size_t)(c0 + cc) * R + r0 + 2 * tx]) = o;
  }
}

// =====================================================================
// preproc_all: ONE pure-BW kernel, full occupancy (no fat LDS pool).
//   [0, 8192)      : convert x f32 -> bf16
//   [8192, 16384)  : transpose+convert w1 [E][H][2I] -> [E][2I][H]
//   [16384, 20480) : transpose+convert w2 [E][I][H]  -> [E][H][I]
// =====================================================================
__global__ __launch_bounds__(256) void preproc_all(
    const float* __restrict__ x, unsigned short* __restrict__ xb,
    const float* __restrict__ w1, unsigned short* __restrict__ w1t,
    const float* __restrict__ w2, unsigned short* __restrict__ w2t) {
  __shared__ float tile[64][33];
  int id = blockIdx.x;
  if (id < 8192) {
    int i = (id * 256 + threadIdx.x) * 4;
    float4 v = *reinterpret_cast<const float4*>(x + i);
    ushort4 o;
    o.x = f2bf(v.x); o.y = f2bf(v.y); o.z = f2bf(v.z); o.w = f2bf(v.w);
    *reinterpret_cast<ushort4*>(xb + i) = o;
    return;
  }
  if (id < 16384) {
    int tb = id - 8192;                     // w1: R=H_, C=2I -> 64 x 16 x 8
    int bx = tb & 63, by = (tb >> 6) & 15, bz = tb >> 10;
    transpose_role(w1 + (size_t)bz * H_ * 2 * I_,
                   w1t + (size_t)bz * H_ * 2 * I_, H_, 2 * I_, bx, by, tile);
    return;
  }
  int tb = id - 16384;                      // w2: R=I_, C=H_ -> 32 x 16 x 8
  int bx = tb & 31, by = (tb >> 5) & 15, bz = tb >> 9;
  transpose_role(w2 + (size_t)bz * I_ * H_,
                 w2t + (size_t)bz * I_ * H_, I_, H_, bx, by, tile);
}

// =====================================================================
// GEMM1 + SwiGLU: X [T][H] bf16 x W1T [E][2I][H] bf16 -> Hout [T][I] bf16
// block: 128 rows x 256 B-rows; 4 waves (1m x 4n), wave 128 x 64, acc[8][4];
// BK=32; 3-buffer ring, vmcnt(12). grid 512 = 8 bn x 64 ty, XCD-swizzled.
// =====================================================================
#define GLDS (BM * BK + 256 * BK)           // shorts per ring buffer (24 KB)
__global__ __launch_bounds__(256, 2) void gemm1_swiglu(
    const unsigned short* __restrict__ X,
    const unsigned short* __restrict__ W1T,
    const int* __restrict__ counts,
    unsigned short* __restrict__ Hout) {
  __shared__ unsigned short pool[3 * GLDS];  // 72 KB
  int id = blockIdx.x;
  int swz = (id & 7) * 64 + (id >> 3);      // 512 % 8 == 0, bijective
  int bn = swz & 7;                          // h block (128 wide)
  int tyid = swz >> 3;                       // M tile 0..63
  int row_start, rows, expert;
  find_tile(counts, tyid, row_start, rows, expert);
  int tid = threadIdx.x, wid = tid >> 6, lane = tid & 63;
  const unsigned short* Wp = W1T + (size_t)expert * (2 * I_) * H_;

  f32x4 acc[8][4];
  #pragma unroll
  for (int m = 0; m < 8; ++m)
    #pragma unroll
    for (int n = 0; n < 4; ++n) acc[m][n] = {0.f, 0.f, 0.f, 0.f};

  int l4 = lane >> 2;
  int csw = ((lane & 3) ^ ((l4 >> 1) & 3)) * 8;   // pre-swizzled global k-chunk
  int lr = lane & 15;
  int ck = ((lane >> 4) ^ ((lr >> 1) & 3)) * 8;   // swizzled ds_read k-chunk

  // per-thread: 2 A + 4 B = 6 gload_lds per tile
#define STAGE1(buf, kt) do {                                                   \
    int k0 = (kt) * BK + csw;                                                  \
    unsigned short* Ab = pool + (buf) * GLDS;                                  \
    unsigned short* Bb = Ab + BM * BK;                                         \
    _Pragma("unroll")                                                          \
    for (int i = 0; i < 2; ++i) {                                              \
      int r = wid * 32 + i * 16;                                               \
      int gr = row_start + min(r + l4, rows - 1);                              \
      gload_lds16(X + (size_t)gr * H_ + k0, Ab + r * BK);                      \
    }                                                                          \
    _Pragma("unroll")                                                          \
    for (int i = 0; i < 4; ++i) {                                              \
      int r = wid * 64 + i * 16;                                               \
      int rb = r + l4;                                                         \
      int sub = rb & 63, ow = rb >> 6;                                         \
      int col = (sub < 32) ? (bn * 128 + ow * 32 + sub)                        \
                           : (I_ + bn * 128 + ow * 32 + sub - 32);             \
      gload_lds16(Wp + (size_t)col * H_ + k0, Bb + r * BK);                    \
    }                                                                          \
  } while (0)

  STAGE1(0, 0);
  STAGE1(1, 1);
  for (int kt = 0; kt < NKT; ++kt) {
    STAGE1((kt + 2) % 3, min(kt + 2, NKT - 1));
    asm volatile("s_waitcnt vmcnt(12)" ::: "memory");
    __builtin_amdgcn_sched_barrier(0);
    __builtin_amdgcn_s_barrier();
    const unsigned short* Ab = pool + (kt % 3) * GLDS;
    const unsigned short* Bb = Ab + BM * BK;
    bf16x8 a[8], b[4];
    #pragma unroll
    for (int m = 0; m < 8; ++m)
      a[m] = *reinterpret_cast<const bf16x8*>(&Ab[(m * 16 + lr) * BK + ck]);
    #pragma unroll
    for (int n = 0; n < 4; ++n)
      b[n] = *reinterpret_cast<const bf16x8*>(&Bb[(wid * 64 + n * 16 + lr) * BK + ck]);
    __builtin_amdgcn_s_setprio(1);
    #pragma unroll
    for (int m = 0; m < 8; ++m)
      #pragma unroll
      for (int n = 0; n < 4; ++n)
        acc[m][n] = __builtin_amdgcn_mfma_f32_16x16x32_bf16(a[m], b[n], acc[m][n], 0, 0, 0);
    __builtin_amdgcn_s_setprio(0);
    __builtin_amdgcn_s_barrier();
  }
#undef STAGE1

  int lq = lane >> 4;
  #pragma unroll
  for (int m = 0; m < 8; ++m)
    #pragma unroll
    for (int n = 0; n < 2; ++n) {
      f32x4 g = acc[m][n], u = acc[m][n + 2];
      #pragma unroll
      for (int r = 0; r < 4; ++r) {
        int rl = m * 16 + lq * 4 + r;
        if (rl < rows) {
          float gv = g[r];
          float hv = (gv / (1.f + __expf(-gv))) * u[r];
          Hout[(size_t)(row_start + rl) * I_ + bn * 128 + wid * 32 + n * 16 + lr] = f2bf(hv);
        }
      }
    }
}

// =====================================================================
// GEMM2: Hin [T][I] bf16 x W2T [E][H][I] bf16 -> Out [T][H] f32
// block 128 x 256, 4 waves (1m x 4n), wave 128x64, acc[8][4];
// 3-ring, vmcnt(12). grid 256 = 4 bn x 64 ty.
// =====================================================================
__global__ __launch_bounds__(256, 2) void gemm2(
    const unsigned short* __restrict__ Hin,
    const unsigned short* __restrict__ W2T,
    const int* __restrict__ counts,
    float* __restrict__ Out) {
  __shared__ unsigned short pool[3 * GLDS];  // 72 KB
  int id = blockIdx.x;
  int swz = (id & 7) * 32 + (id >> 3);       // 256 % 8 == 0
  int bn = swz & 3;                           // out col block (256 wide)
  int tyid = swz >> 2;
  int row_start, rows, expert;
  find_tile(counts, tyid, row_start, rows, expert);
  int tid = threadIdx.x, wid = tid >> 6, lane = tid & 63;
  const unsigned short* Wp = W2T + (size_t)expert * H_ * I_;

  f32x4 acc[8][4];
  #pragma unroll
  for (int m = 0; m < 8; ++m)
    #pragma unroll
    for (int n = 0; n < 4; ++n) acc[m][n] = {0.f, 0.f, 0.f, 0.f};

  int l4 = lane >> 2;
  int csw = ((lane & 3) ^ ((l4 >> 1) & 3)) * 8;
  int lr = lane & 15;
  int ck = ((lane >> 4) ^ ((lr >> 1) & 3)) * 8;

  // per-thread: 2 A + 4 B = 6 gload_lds per tile
#define STAGE2(buf, kt) do {                                                   \
    int k0 = (kt) * BK + csw;                                                  \
    unsigned short* Ab = pool + (buf) * GLDS;                                  \
    unsigned short* Bb = Ab + BM * BK;                                         \
    _Pragma("unroll")                                                          \
    for (int i = 0; i < 2; ++i) {                                              \
      int r = wid * 32 + i * 16;                                               \
      int gr = row_start + min(r + l4, rows - 1);                              \
      gload_lds16(Hin + (size_t)gr * I_ + k0, Ab + r * BK);                    \
    }                                                                          \
    _Pragma("unroll")                                                          \
    for (int i = 0; i < 4; ++i) {                                              \
      int r = wid * 64 + i * 16;                                               \
      int col = bn * 256 + r + l4;                                             \
      gload_lds16(Wp + (size_t)col * I_ + k0, Bb + r * BK);                    \
    }                                                                          \
  } while (0)

  STAGE2(0, 0);
  STAGE2(1, 1);
  for (int kt = 0; kt < NKT; ++kt) {
    STAGE2((kt + 2) % 3, min(kt + 2, NKT - 1));
    asm volatile("s_waitcnt vmcnt(12)" ::: "memory");
    __builtin_amdgcn_sched_barrier(0);
    __builtin_amdgcn_s_barrier();
    const unsigned short* Ab = pool + (kt % 3) * GLDS;
    const unsigned short* Bb = Ab + BM * BK;
    bf16x8 a[8], b[4];
    #pragma unroll
    for (int m = 0; m < 8; ++m)
      a[m] = *reinterpret_cast<const bf16x8*>(&Ab[(m * 16 + lr) * BK + ck]);
    #pragma unroll
    for (int n = 0; n < 4; ++n)
      b[n] = *reinterpret_cast<const bf16x8*>(&Bb[(wid * 64 + n * 16 + lr) * BK + ck]);
    __builtin_amdgcn_s_setprio(1);
    #pragma unroll
    for (int m = 0; m < 8; ++m)
      #pragma unroll
      for (int n = 0; n < 4; ++n)
        acc[m][n] = __builtin_amdgcn_mfma_f32_16x16x32_bf16(a[m], b[n], acc[m][n], 0, 0, 0);
    __builtin_amdgcn_s_setprio(0);
    __builtin_amdgcn_s_barrier();
  }
#undef STAGE2

  int lq = lane >> 4;
  #pragma unroll
  for (int m = 0; m < 8; ++m)
    #pragma unroll
    for (int n = 0; n < 4; ++n)
      #pragma unroll
      for (int r = 0; r < 4; ++r) {
        int rl = m * 16 + lq * 4 + r;
        if (rl < rows)
          Out[(size_t)(row_start + rl) * H_ + bn * 256 + wid * 64 + n * 16 + lr] =
              acc[m][n][r];
      }
}

extern "C" void kernel_launch(void* const* d_in, const int* in_sizes, int n_in,
                              void* d_out, int out_size, void* d_ws, size_t ws_size,
                              hipStream_t stream) {
  const float* x  = (const float*)d_in[0];
  const float* w1 = (const float*)d_in[1];   // [E][H][2I]
  const float* w2 = (const float*)d_in[2];   // [E][I][H]
  const int* counts = (const int*)d_in[3];
  float* out = (float*)d_out;

  char* ws = (char*)d_ws;
  unsigned short* xb  = (unsigned short*)ws;
  unsigned short* w1t = (unsigned short*)(ws + (size_t)T_ * H_ * 2);
  unsigned short* w2t = (unsigned short*)(ws + (size_t)T_ * H_ * 2
                                             + (size_t)E_ * 2 * I_ * H_ * 2);
  unsigned short* hbuf = (unsigned short*)(ws + (size_t)T_ * H_ * 2
                                              + (size_t)E_ * 2 * I_ * H_ * 2
                                              + (size_t)E_ * H_ * I_ * 2);

  // 1) all preprocessing in one full-occupancy BW kernel
  preproc_all<<<20480, 256, 0, stream>>>(x, xb, w1, w1t, w2, w2t);
  // 2) grouped GEMM1 + SwiGLU
  gemm1_swiglu<<<512, 256, 0, stream>>>(xb, w1t, counts, hbuf);
  // 3) grouped GEMM2
  gemm2<<<256, 256, 0, stream>>>(hbuf, w2t, counts, out);
}

// Round 8
// 101.576 us; speedup vs baseline: 1.3337x; 1.0024x over previous
//
#include <hip/hip_runtime.h>
#include <hip/hip_bf16.h>
#include <stdint.h>

#define E_ 8
#define H_ 1024
#define I_ 1024
#define T_ 8192
#define BM 128
#define BK 32
#define NKT 32

typedef __attribute__((ext_vector_type(4))) float f32x4;
typedef __attribute__((ext_vector_type(8))) short bf16x8;

__device__ __forceinline__ unsigned short f2bf(float f) {
  union { float f; unsigned int u; } v; v.f = f;
  unsigned int lsb = (v.u >> 16) & 1u;
  v.u += 0x7fffu + lsb;          // RNE
  return (unsigned short)(v.u >> 16);
}

__device__ __forceinline__ void gload_lds16(const void* g, void* l) {
  __builtin_amdgcn_global_load_lds(
      (const __attribute__((address_space(1))) unsigned int*)g,
      (__attribute__((address_space(3))) unsigned int*)l,
      16, 0, 0);
}

// ------------- expert lookup -------------
__device__ __forceinline__ void find_tile(const int* counts, int ty,
                                          int& row_start, int& rows, int& expert) {
  int tacc = 0, off = 0;
  expert = 0; row_start = 0; rows = BM;
  #pragma unroll
  for (int e = 0; e < E_; ++e) {
    int c = counts[e];
    int te = (c + BM - 1) >> 7;
    if (ty >= tacc && ty < tacc + te) {
      expert = e;
      int lt = ty - tacc;
      row_start = off + lt * BM;
      rows = min(BM, c - lt * BM);
    }
    tacc += te; off += c;
  }
}

// ---------- transpose role v2: vectorized both global sides ----------
// [R][C] f32 -> [C][R] bf16 ; in-tile 128 rows x 64 cols per block (256 thr)
// loads: float4 (16 B/lane); stores: ushort4 (8 B/lane, 256 B segments)
// LDS [128][65] f32: write banks (r+4c+j) mod 32 -> 2-way (free);
// column-gather read banks (4l+i+cc) mod 32 -> 4-way (1.58x, acceptable)
__device__ __forceinline__ void transpose_role(const float* __restrict__ inp,
                                               unsigned short* __restrict__ outp,
                                               int R, int C, int bx, int by,
                                               float* tile /* [128*65] */) {
  int c0 = bx * 64, r0 = by * 128;
  int lc = threadIdx.x & 15;        // float4 col group (16 x 4 = 64 cols)
  int lrw = threadIdx.x >> 4;       // 0..15 rows per pass
  #pragma unroll
  for (int p = 0; p < 8; ++p) {
    int r = p * 16 + lrw;
    float4 v = *reinterpret_cast<const float4*>(
        inp + (size_t)(r0 + r) * C + c0 + lc * 4);
    float* t = &tile[r * 65 + lc * 4];
    t[0] = v.x; t[1] = v.y; t[2] = v.z; t[3] = v.w;
  }
  __syncthreads();
  int l32 = threadIdx.x & 31;       // r-chunk (4 f32) within out row
  int occ = threadIdx.x >> 5;       // 0..7 out rows per pass
  #pragma unroll
  for (int p = 0; p < 8; ++p) {
    int cc = p * 8 + occ;           // 64 out rows
    ushort4 o;
    o.x = f2bf(tile[(4 * l32 + 0) * 65 + cc]);
    o.y = f2bf(tile[(4 * l32 + 1) * 65 + cc]);
    o.z = f2bf(tile[(4 * l32 + 2) * 65 + cc]);
    o.w = f2bf(tile[(4 * l32 + 3) * 65 + cc]);
    *reinterpret_cast<ushort4*>(&outp[(size_t)(c0 + cc) * R + r0 + 4 * l32]) = o;
  }
}

// =====================================================================
// preproc_all: ONE pure-BW kernel.
//   [0, 2048)     : convert x f32 -> bf16 (grid-stride x4, 16 KB/block)
//   [2048, 4096)  : transpose+convert w1 [E][H][2I] -> [E][2I][H]
//   [4096, 5120)  : transpose+convert w2 [E][I][H]  -> [E][H][I]
// =====================================================================
__global__ __launch_bounds__(256) void preproc_all(
    const float* __restrict__ x, unsigned short* __restrict__ xb,
    const float* __restrict__ w1, unsigned short* __restrict__ w1t,
    const float* __restrict__ w2, unsigned short* __restrict__ w2t) {
  __shared__ float tile[128 * 65];
  int id = blockIdx.x;
  if (id < 2048) {
    #pragma unroll
    for (int it = 0; it < 4; ++it) {
      int i = id * 4096 + it * 1024 + threadIdx.x * 4;
      float4 v = *reinterpret_cast<const float4*>(x + i);
      ushort4 o;
      o.x = f2bf(v.x); o.y = f2bf(v.y); o.z = f2bf(v.z); o.w = f2bf(v.w);
      *reinterpret_cast<ushort4*>(xb + i) = o;
    }
    return;
  }
  if (id < 4096) {
    int tb = id - 2048;                     // w1: R=H_, C=2I -> 32 x 8 x 8
    int bx = tb & 31, by = (tb >> 5) & 7, bz = tb >> 8;
    transpose_role(w1 + (size_t)bz * H_ * 2 * I_,
                   w1t + (size_t)bz * H_ * 2 * I_, H_, 2 * I_, bx, by, tile);
    return;
  }
  int tb = id - 4096;                       // w2: R=I_, C=H_ -> 16 x 8 x 8
  int bx = tb & 15, by = (tb >> 4) & 7, bz = tb >> 7;
  transpose_role(w2 + (size_t)bz * I_ * H_,
                 w2t + (size_t)bz * I_ * H_, I_, H_, bx, by, tile);
}

// =====================================================================
// GEMM1 + SwiGLU: X [T][H] bf16 x W1T [E][2I][H] bf16 -> Hout [T][I] bf16
// block: 128 rows x 256 B-rows; 4 waves (1m x 4n), wave 128 x 64, acc[8][4];
// BK=32; 3-buffer ring, vmcnt(12). grid 512 = 8 bn x 64 ty, XCD-swizzled.
// =====================================================================
#define GLDS (BM * BK + 256 * BK)           // shorts per ring buffer (24 KB)
__global__ __launch_bounds__(256, 2) void gemm1_swiglu(
    const unsigned short* __restrict__ X,
    const unsigned short* __restrict__ W1T,
    const int* __restrict__ counts,
    unsigned short* __restrict__ Hout) {
  __shared__ unsigned short pool[3 * GLDS];  // 72 KB
  int id = blockIdx.x;
  int swz = (id & 7) * 64 + (id >> 3);      // 512 % 8 == 0, bijective
  int bn = swz & 7;                          // h block (128 wide)
  int tyid = swz >> 3;                       // M tile 0..63
  int row_start, rows, expert;
  find_tile(counts, tyid, row_start, rows, expert);
  int tid = threadIdx.x, wid = tid >> 6, lane = tid & 63;
  const unsigned short* Wp = W1T + (size_t)expert * (2 * I_) * H_;

  f32x4 acc[8][4];
  #pragma unroll
  for (int m = 0; m < 8; ++m)
    #pragma unroll
    for (int n = 0; n < 4; ++n) acc[m][n] = {0.f, 0.f, 0.f, 0.f};

  int l4 = lane >> 2;
  int csw = ((lane & 3) ^ ((l4 >> 1) & 3)) * 8;   // pre-swizzled global k-chunk
  int lr = lane & 15;
  int ck = ((lane >> 4) ^ ((lr >> 1) & 3)) * 8;   // swizzled ds_read k-chunk

  // per-thread: 2 A + 4 B = 6 gload_lds per tile
#define STAGE1(buf, kt) do {                                                   \
    int k0 = (kt) * BK + csw;                                                  \
    unsigned short* Ab = pool + (buf) * GLDS;                                  \
    unsigned short* Bb = Ab + BM * BK;                                         \
    _Pragma("unroll")                                                          \
    for (int i = 0; i < 2; ++i) {                                              \
      int r = wid * 32 + i * 16;                                               \
      int gr = row_start + min(r + l4, rows - 1);                              \
      gload_lds16(X + (size_t)gr * H_ + k0, Ab + r * BK);                      \
    }                                                                          \
    _Pragma("unroll")                                                          \
    for (int i = 0; i < 4; ++i) {                                              \
      int r = wid * 64 + i * 16;                                               \
      int rb = r + l4;                                                         \
      int sub = rb & 63, ow = rb >> 6;                                         \
      int col = (sub < 32) ? (bn * 128 + ow * 32 + sub)                        \
                           : (I_ + bn * 128 + ow * 32 + sub - 32);             \
      gload_lds16(Wp + (size_t)col * H_ + k0, Bb + r * BK);                    \
    }                                                                          \
  } while (0)

  STAGE1(0, 0);
  STAGE1(1, 1);
  for (int kt = 0; kt < NKT; ++kt) {
    STAGE1((kt + 2) % 3, min(kt + 2, NKT - 1));
    asm volatile("s_waitcnt vmcnt(12)" ::: "memory");
    __builtin_amdgcn_sched_barrier(0);
    __builtin_amdgcn_s_barrier();
    const unsigned short* Ab = pool + (kt % 3) * GLDS;
    const unsigned short* Bb = Ab + BM * BK;
    bf16x8 a[8], b[4];
    #pragma unroll
    for (int m = 0; m < 8; ++m)
      a[m] = *reinterpret_cast<const bf16x8*>(&Ab[(m * 16 + lr) * BK + ck]);
    #pragma unroll
    for (int n = 0; n < 4; ++n)
      b[n] = *reinterpret_cast<const bf16x8*>(&Bb[(wid * 64 + n * 16 + lr) * BK + ck]);
    __builtin_amdgcn_s_setprio(1);
    #pragma unroll
    for (int m = 0; m < 8; ++m)
      #pragma unroll
      for (int n = 0; n < 4; ++n)
        acc[m][n] = __builtin_amdgcn_mfma_f32_16x16x32_bf16(a[m], b[n], acc[m][n], 0, 0, 0);
    __builtin_amdgcn_s_setprio(0);
    __builtin_amdgcn_s_barrier();
  }
#undef STAGE1

  int lq = lane >> 4;
  #pragma unroll
  for (int m = 0; m < 8; ++m)
    #pragma unroll
    for (int n = 0; n < 2; ++n) {
      f32x4 g = acc[m][n], u = acc[m][n + 2];
      #pragma unroll
      for (int r = 0; r < 4; ++r) {
        int rl = m * 16 + lq * 4 + r;
        if (rl < rows) {
          float gv = g[r];
          float hv = (gv / (1.f + __expf(-gv))) * u[r];
          Hout[(size_t)(row_start + rl) * I_ + bn * 128 + wid * 32 + n * 16 + lr] = f2bf(hv);
        }
      }
    }
}

// =====================================================================
// GEMM2: Hin [T][I] bf16 x W2T [E][H][I] bf16 -> Out [T][H] f32
// block 128 x 256, 4 waves (1m x 4n), wave 128x64, acc[8][4];
// 3-ring, vmcnt(12). grid 256 = 4 bn x 64 ty.
// =====================================================================
__global__ __launch_bounds__(256, 2) void gemm2(
    const unsigned short* __restrict__ Hin,
    const unsigned short* __restrict__ W2T,
    const int* __restrict__ counts,
    float* __restrict__ Out) {
  __shared__ unsigned short pool[3 * GLDS];  // 72 KB
  int id = blockIdx.x;
  int swz = (id & 7) * 32 + (id >> 3);       // 256 % 8 == 0
  int bn = swz & 3;                           // out col block (256 wide)
  int tyid = swz >> 2;
  int row_start, rows, expert;
  find_tile(counts, tyid, row_start, rows, expert);
  int tid = threadIdx.x, wid = tid >> 6, lane = tid & 63;
  const unsigned short* Wp = W2T + (size_t)expert * H_ * I_;

  f32x4 acc[8][4];
  #pragma unroll
  for (int m = 0; m < 8; ++m)
    #pragma unroll
    for (int n = 0; n < 4; ++n) acc[m][n] = {0.f, 0.f, 0.f, 0.f};

  int l4 = lane >> 2;
  int csw = ((lane & 3) ^ ((l4 >> 1) & 3)) * 8;
  int lr = lane & 15;
  int ck = ((lane >> 4) ^ ((lr >> 1) & 3)) * 8;

  // per-thread: 2 A + 4 B = 6 gload_lds per tile
#define STAGE2(buf, kt) do {                                                   \
    int k0 = (kt) * BK + csw;                                                  \
    unsigned short* Ab = pool + (buf) * GLDS;                                  \
    unsigned short* Bb = Ab + BM * BK;                                         \
    _Pragma("unroll")                                                          \
    for (int i = 0; i < 2; ++i) {                                              \
      int r = wid * 32 + i * 16;                                               \
      int gr = row_start + min(r + l4, rows - 1);                              \
      gload_lds16(Hin + (size_t)gr * I_ + k0, Ab + r * BK);                    \
    }                                                                          \
    _Pragma("unroll")                                                          \
    for (int i = 0; i < 4; ++i) {                                              \
      int r = wid * 64 + i * 16;                                               \
      int col = bn * 256 + r + l4;                                             \
      gload_lds16(Wp + (size_t)col * I_ + k0, Bb + r * BK);                    \
    }                                                                          \
  } while (0)

  STAGE2(0, 0);
  STAGE2(1, 1);
  for (int kt = 0; kt < NKT; ++kt) {
    STAGE2((kt + 2) % 3, min(kt + 2, NKT - 1));
    asm volatile("s_waitcnt vmcnt(12)" ::: "memory");
    __builtin_amdgcn_sched_barrier(0);
    __builtin_amdgcn_s_barrier();
    const unsigned short* Ab = pool + (kt % 3) * GLDS;
    const unsigned short* Bb = Ab + BM * BK;
    bf16x8 a[8], b[4];
    #pragma unroll
    for (int m = 0; m < 8; ++m)
      a[m] = *reinterpret_cast<const bf16x8*>(&Ab[(m * 16 + lr) * BK + ck]);
    #pragma unroll
    for (int n = 0; n < 4; ++n)
      b[n] = *reinterpret_cast<const bf16x8*>(&Bb[(wid * 64 + n * 16 + lr) * BK + ck]);
    __builtin_amdgcn_s_setprio(1);
    #pragma unroll
    for (int m = 0; m < 8; ++m)
      #pragma unroll
      for (int n = 0; n < 4; ++n)
        acc[m][n] = __builtin_amdgcn_mfma_f32_16x16x32_bf16(a[m], b[n], acc[m][n], 0, 0, 0);
    __builtin_amdgcn_s_setprio(0);
    __builtin_amdgcn_s_barrier();
  }
#undef STAGE2

  int lq = lane >> 4;
  #pragma unroll
  for (int m = 0; m < 8; ++m)
    #pragma unroll
    for (int n = 0; n < 4; ++n)
      #pragma unroll
      for (int r = 0; r < 4; ++r) {
        int rl = m * 16 + lq * 4 + r;
        if (rl < rows)
          Out[(size_t)(row_start + rl) * H_ + bn * 256 + wid * 64 + n * 16 + lr] =
              acc[m][n][r];
      }
}

extern "C" void kernel_launch(void* const* d_in, const int* in_sizes, int n_in,
                              void* d_out, int out_size, void* d_ws, size_t ws_size,
                              hipStream_t stream) {
  const float* x  = (const float*)d_in[0];
  const float* w1 = (const float*)d_in[1];   // [E][H][2I]
  const float* w2 = (const float*)d_in[2];   // [E][I][H]
  const int* counts = (const int*)d_in[3];
  float* out = (float*)d_out;

  char* ws = (char*)d_ws;
  unsigned short* xb  = (unsigned short*)ws;
  unsigned short* w1t = (unsigned short*)(ws + (size_t)T_ * H_ * 2);
  unsigned short* w2t = (unsigned short*)(ws + (size_t)T_ * H_ * 2
                                             + (size_t)E_ * 2 * I_ * H_ * 2);
  unsigned short* hbuf = (unsigned short*)(ws + (size_t)T_ * H_ * 2
                                              + (size_t)E_ * 2 * I_ * H_ * 2
                                              + (size_t)E_ * H_ * I_ * 2);

  // 1) all preprocessing, vectorized both directions
  preproc_all<<<5120, 256, 0, stream>>>(x, xb, w1, w1t, w2, w2t);
  // 2) grouped GEMM1 + SwiGLU
  gemm1_swiglu<<<512, 256, 0, stream>>>(xb, w1t, counts, hbuf);
  // 3) grouped GEMM2
  gemm2<<<256, 256, 0, stream>>>(hbuf, w2t, counts, out);
}